// Round 11
// baseline (199.841 us; speedup 1.0000x reference)
//
#include <hip/hip_runtime.h>
#include <hip/hip_fp16.h>

typedef unsigned long long ull;
typedef unsigned short ushort_t;
typedef unsigned int u32;
typedef short bf16x8 __attribute__((ext_vector_type(8)));
typedef _Float16 f16x8 __attribute__((ext_vector_type(8)));
typedef float f32x4 __attribute__((ext_vector_type(4)));

#define NC 10000   // H*W cells
#define D_ 256     // input dim
#define B_ 1024    // batch
#define W_ 100     // grid width
#define NT 79      // score c-tiles (128 cells each)
#define PKS 160    // pkt row stride in ull
#define TAU 0.10f  // >= 2*eps_score for fp16-input MFMA scores (proven R7/R9/R10)
#define MAXC 16    // parallel exact-path blocks per sample

// async global->LDS, 16B per lane; LDS dest = wave-uniform base + lane*16
__device__ __forceinline__ void gl_lds16(const void* g, void* l) {
    __builtin_amdgcn_global_load_lds(
        (const __attribute__((address_space(1))) u32*)g,
        (__attribute__((address_space(3))) u32*)l,
        16, 0, 0);
}

// bijective XCD-chunk swizzle (m204)
__device__ __forceinline__ int xcd_swz(int orig, int nwg) {
    int q = nwg >> 3, r = nwg & 7;
    int xcd = orig & 7, off = orig >> 3;
    return (xcd < r ? xcd * (q + 1) : r * (q + 1) + (xcd - r) * q) + off;
}

// monotonic float -> sortable uint mapping
__device__ __forceinline__ unsigned fkey(float f) {
    unsigned u = __float_as_uint(f);
    return (u & 0x80000000u) ? ~u : (u | 0x80000000u);
}
__device__ __forceinline__ float unfkey(unsigned k) {
    unsigned u = (k & 0x80000000u) ? (k ^ 0x80000000u) : ~k;
    return __uint_as_float(u);
}

// exact RNE float -> bf16 bits
__device__ __forceinline__ ushort_t f2bf(float f) {
    unsigned u = __float_as_uint(f);
    unsigned r = (u + 0x7fffu + ((u >> 16) & 1u)) >> 16;
    return (ushort_t)r;
}

__device__ __forceinline__ void decay_params(const int* ep, const int* tp, float& lr, float& inv2r2) {
    double decay = 1.0 - (double)(*ep) / (double)(*tp);
    lr = (float)(0.5 * decay);
    float radius = (float)(50.0 * decay);
    inv2r2 = 1.0f / (2.0f * radius * radius);
}

// sorted-pair merge: (a1,a2) <- two smallest of {a1,a2,c1,c2}  (a1<=a2, c1<=c2)
__device__ __forceinline__ void merge2(ull& a1, ull& a2, ull c1, ull c2) {
    ull m1 = a1 < c1 ? a1 : c1;
    ull hi = a1 < c1 ? c1 : a1;
    ull lo2 = a2 < c2 ? a2 : c2;
    a2 = hi < lo2 ? hi : lo2;
    a1 = m1;
}

// fused prep: blocks [0,2500) = w -> wh fp16 + wnorm; blocks [2500,2564) = x -> xh fp16 + xhT bf16
__global__ __launch_bounds__(256) void k_prep(const float* __restrict__ w, const float* __restrict__ x,
                                              __half* __restrict__ wh, float* __restrict__ wnorm,
                                              __half* __restrict__ xh, ushort_t* __restrict__ xhT) {
    int bid = blockIdx.x;
    int tid = threadIdx.x;
    if (bid < NC / 4) {
        int cell = bid * 4 + (tid >> 6);
        int lane = tid & 63;
        float4 v = *reinterpret_cast<const float4*>(&w[(size_t)cell * D_ + lane * 4]);
        float s = v.x * v.x + v.y * v.y + v.z * v.z + v.w * v.w;
        __half hb[4];
        float e[4] = {v.x, v.y, v.z, v.w};
        #pragma unroll
        for (int i = 0; i < 4; ++i) hb[i] = __float2half(e[i]);
        *reinterpret_cast<uint2*>(&wh[(size_t)cell * D_ + lane * 4]) = *reinterpret_cast<uint2*>(hb);
        #pragma unroll
        for (int off = 32; off; off >>= 1) s += __shfl_xor(s, off);
        if (lane == 0) wnorm[cell] = s;
    } else {
        __shared__ ushort_t tile[64][65];
        int idx = bid - NC / 4;
        int b0 = (idx & 15) * 64, d0 = (idx >> 4) * 64;
        #pragma unroll
        for (int r = 0; r < 16; ++r) {
            int f = r * 256 + tid;
            int i = f >> 6, j = f & 63;       // i = b-local, j = d-local
            float v = x[(size_t)(b0 + i) * D_ + d0 + j];
            xh[(size_t)(b0 + i) * D_ + d0 + j] = __float2half(v);
            tile[j][i] = f2bf(v);
        }
        __syncthreads();
        #pragma unroll
        for (int r = 0; r < 2; ++r) {
            int f = r * 256 + tid;            // [0,512): 64 d-rows x 8 units
            int row = f >> 3, u = f & 7;
            ushort_t v[8];
            #pragma unroll
            for (int e = 0; e < 8; ++e) v[e] = tile[row][u * 8 + e];
            *reinterpret_cast<uint4*>(&xhT[(size_t)(d0 + row) * B_ + b0 + u * 8]) =
                *reinterpret_cast<uint4*>(v);
        }
    }
}

// fp16 scores GEMM with fused per-tile (min1,min2) epilogue -> pkt[b][tile]
// tile 128 cells x 128 batch, BK=64, 8 waves (2 cell x 4 batch), single-buffer staging
// tile==0 blocks also init doneCnt/packed_fix for their 128 samples (pre-bmu, kernel boundary orders it)
__global__ __launch_bounds__(512) void k_scores_mfma(const __half* __restrict__ wh, const __half* __restrict__ xh,
                                                     const float* __restrict__ wnorm, ull* __restrict__ pkt,
                                                     ull* __restrict__ packed_fix, int* __restrict__ doneCnt) {
    __shared__ __align__(16) __half As[128 * 64];  // cells x k  (16KB)
    __shared__ __align__(16) __half Bs[128 * 64];  // batch x k  (16KB)
    const int tid = threadIdx.x;
    int orig = blockIdx.y * gridDim.x + blockIdx.x;
    int wgid = xcd_swz(orig, 8 * NT);
    const int b0 = (wgid & 7) * 128;
    const int c0 = (wgid >> 3) * 128;
    const int tile = wgid >> 3;
    const int wid = tid >> 6, lane = tid & 63;
    const int wc = wid >> 2;           // 0..1 -> 64 cells
    const int wb = wid & 3;            // 0..3 -> 32 batch
    const int g4 = lane >> 4, l16 = lane & 15;

    f32x4 acc[4][2] = {};

    for (int k0 = 0; k0 < D_; k0 += 64) {
        if (k0) __syncthreads();
        #pragma unroll
        for (int r = 0; r < 2; ++r) {
            int f = tid + r * 512;        // [0,1024): 128 rows x 8 16B-units
            int row = f >> 3, u = f & 7;
            int ug = (u ^ (row & 7)) * 8;
            int cc = c0 + row; if (cc > NC - 1) cc = NC - 1;
            gl_lds16(&wh[(size_t)cc * D_ + k0 + ug], &As[(f & ~63) * 8]);
            gl_lds16(&xh[(size_t)(b0 + row) * D_ + k0 + ug], &Bs[(f & ~63) * 8]);
        }
        __syncthreads();
        #pragma unroll
        for (int kh = 0; kh < 2; ++kh) {
            int ubase = kh * 4 + g4;
            f16x8 bfr[2];
            #pragma unroll
            for (int fn = 0; fn < 2; ++fn) {
                int rowb = wb * 32 + fn * 16 + l16;
                bfr[fn] = *reinterpret_cast<const f16x8*>(&Bs[rowb * 64 + ((ubase ^ (rowb & 7)) * 8)]);
            }
            #pragma unroll
            for (int fm = 0; fm < 4; ++fm) {
                int rowa = wc * 64 + fm * 16 + l16;
                f16x8 af = *reinterpret_cast<const f16x8*>(&As[rowa * 64 + ((ubase ^ (rowa & 7)) * 8)]);
                #pragma unroll
                for (int fn = 0; fn < 2; ++fn)
                    acc[fm][fn] = __builtin_amdgcn_mfma_f32_16x16x32_f16(af, bfr[fn], acc[fm][fn], 0, 0, 0);
            }
        }
    }

    // per-lane (min1,min2) per fn over fm,r; phantom cells predicated out
    ull m1[2] = {~0ull, ~0ull}, m2[2] = {~0ull, ~0ull};
    #pragma unroll
    for (int fm = 0; fm < 4; ++fm) {
        int cb = c0 + wc * 64 + fm * 16 + g4 * 4;
        float4 wn4 = *reinterpret_cast<const float4*>(&wnorm[cb]);  // ws garbage ok for >=NC (masked)
        float wna[4] = {wn4.x, wn4.y, wn4.z, wn4.w};
        #pragma unroll
        for (int fn = 0; fn < 2; ++fn)
            #pragma unroll
            for (int r = 0; r < 4; ++r) {
                float s = wna[r] - 2.0f * acc[fm][fn][r];
                ull p = (cb + r < NC) ? (((ull)fkey(s) << 32) | (unsigned)(cb + r)) : ~0ull;
                merge2(m1[fn], m2[fn], p, ~0ull);
            }
    }
    #pragma unroll
    for (int fn = 0; fn < 2; ++fn) {
        #pragma unroll
        for (int off = 16; off <= 32; off <<= 1) {
            ull o1 = __shfl_xor(m1[fn], off), o2 = __shfl_xor(m2[fn], off);
            merge2(m1[fn], m2[fn], o1, o2);
        }
    }
    __syncthreads();                   // all MFMA LDS reads done before As reuse
    ull* sm1 = (ull*)&As[0];           // [2][128]
    ull* sm2 = sm1 + 256;
    if (g4 == 0) {
        #pragma unroll
        for (int fn = 0; fn < 2; ++fn) {
            int bl = wb * 32 + fn * 16 + l16;
            sm1[wc * 128 + bl] = m1[fn];
            sm2[wc * 128 + bl] = m2[fn];
        }
    }
    __syncthreads();
    if (tid < 128) {
        ull a1 = sm1[tid], a2 = sm2[tid];
        merge2(a1, a2, sm1[128 + tid], sm2[128 + tid]);
        size_t base = (size_t)(b0 + tid) * PKS + tile * 2;
        pkt[base] = a1;
        pkt[base + 1] = a2;
    }
    if (tile == 0 && tid < 128) {      // init for k_bmu (8 such blocks cover all 1024 samples)
        doneCnt[b0 + tid] = 0;
        packed_fix[b0 + tid] = ~0ull;
    }
}

// single-dispatch BMU: grid (MAXC, B_). Every block merges its sample's 79 pairs (L2-hot).
// Certain -> block j=0 writes bxy. Flagged -> deterministic ballot-prefix candidate list
// (identical in all 16 blocks), block j handles tiles j, j+16, ...; atomicMin + fenced
// done-counter; 16th block decodes.
__global__ __launch_bounds__(256) void k_bmu(const ull* __restrict__ pkt, const float* __restrict__ x,
                                             const float* __restrict__ w, ull* __restrict__ packed_fix,
                                             int* __restrict__ doneCnt, int2* __restrict__ bxy) {
    __shared__ ull s1[2], s2[2];
    __shared__ int candList[NT];
    __shared__ int scnt[2];
    __shared__ ull sb[4];
    int j = blockIdx.x;                // 0..MAXC-1
    int b = blockIdx.y;
    int tid = threadIdx.x, lane = tid & 63, wv = tid >> 6;

    ull mt1 = ~0ull, mt2 = ~0ull;
    if (tid < NT) {
        mt1 = pkt[(size_t)b * PKS + tid * 2];
        mt2 = pkt[(size_t)b * PKS + tid * 2 + 1];
    }
    if (wv < 2) {
        ull a1 = mt1, a2 = mt2;
        #pragma unroll
        for (int off = 1; off <= 32; off <<= 1) {
            ull o1 = __shfl_xor(a1, off), o2 = __shfl_xor(a2, off);
            merge2(a1, a2, o1, o2);
        }
        if (lane == 0) { s1[wv] = a1; s2[wv] = a2; }
    }
    __syncthreads();
    ull a1 = s1[0], a2 = s2[0];
    merge2(a1, a2, s1[1], s2[1]);
    float f1 = unfkey((unsigned)(a1 >> 32));
    float f2 = unfkey((unsigned)(a2 >> 32));
    if (f2 - f1 >= TAU) {              // uniform: identical across all blocks of this sample
        if (j == 0 && tid == 0) {
            int c = (int)(unsigned)(a1 & 0xffffffffull);
            bxy[b] = make_int2(c / W_, c % W_);
        }
        return;
    }
    // deterministic candidate list (ballot-prefix; lanes of waves 0,1 <-> tiles)
    bool pred = (tid < NT) && (unfkey((unsigned)(mt1 >> 32)) <= f1 + TAU);
    ull bal = __ballot(pred);
    if (wv < 2 && lane == 0) scnt[wv] = (int)__popcll(bal);
    __syncthreads();
    if (pred) {
        int idx = ((wv == 1) ? scnt[0] : 0) + (int)__popcll(bal & ((1ull << lane) - 1ull));
        candList[idx] = tid;
    }
    __syncthreads();
    int n = scnt[0] + scnt[1];

    float4 xv = *reinterpret_cast<const float4*>(&x[(size_t)b * D_ + lane * 4]);
    ull best = ~0ull;
    for (int ci = j; ci < n; ci += MAXC) {
        int t = candList[ci];
        #pragma unroll 4
        for (int i = wv; i < 128; i += 4) {   // 4 waves x unroll-4 independent streams
            int c = t * 128 + i;
            if (c < NC) {
                float4 wv4 = *reinterpret_cast<const float4*>(&w[(size_t)c * D_ + lane * 4]);
                float p = wv4.x * (wv4.x - 2.0f * xv.x) + wv4.y * (wv4.y - 2.0f * xv.y)
                        + wv4.z * (wv4.z - 2.0f * xv.z) + wv4.w * (wv4.w - 2.0f * xv.w);
                #pragma unroll
                for (int off = 32; off; off >>= 1) p += __shfl_xor(p, off);
                if (lane == 0) {
                    ull pk = ((ull)fkey(p) << 32) | (unsigned)c;
                    best = pk < best ? pk : best;
                }
            }
        }
    }
    if (lane == 0) sb[wv] = best;
    __syncthreads();
    if (tid == 0) {
        best = sb[0];
        #pragma unroll
        for (int k = 1; k < 4; ++k) best = sb[k] < best ? sb[k] : best;
        if (best != ~0ull) atomicMin(&packed_fix[b], best);
        __threadfence();
        int old = atomicAdd(&doneCnt[b], 1);
        if (old == MAXC - 1) {         // last block: all mins visible (fence + RMW chain)
            __threadfence();
            ull fin = packed_fix[b];
            int c = (int)(unsigned)(fin & 0xffffffffull);
            bxy[b] = make_int2(c / W_, c % W_);
        }
    }
}

// chunked 2-pass suffix scan with separable-Gaussian LDS table
__global__ __launch_bounds__(256) void k_scan(const int2* __restrict__ bxy, const int* __restrict__ ep,
                                              const int* __restrict__ tp, ushort_t* __restrict__ coefT,
                                              float* __restrict__ T) {
    __shared__ float E[W_];
    float lr, inv2r2;
    decay_params(ep, tp, lr, inv2r2);
    if (threadIdx.x < W_) {
        float d = (float)threadIdx.x;
        E[threadIdx.x] = __expf(-d * d * inv2r2);
    }
    __syncthreads();

    int g = blockIdx.x * 256 + threadIdx.x;
    int c = g >> 3, t = g & 7;
    if (c >= NC) return;
    int cy = c / W_, cx = c % W_;
    int base = t * 128;

    float P = 1.0f;
    for (int i = base; i < base + 128; ++i) {
        int2 p = bxy[i];
        int dy = abs(p.x - cy), dx = abs(p.y - cx);
        float a = lr * E[dy] * E[dx];
        P *= (1.0f - a);
    }
    int gbase = (threadIdx.x & 63) & ~7;
    float M = 1.0f;
    #pragma unroll
    for (int k = 1; k < 8; ++k) {
        float pk = __shfl(P, gbase + k, 64);
        if (k > t) M *= pk;
    }
    if (t == 0) T[c] = M * P;

    float s = M;
    for (int seg = 15; seg >= 0; --seg) {
        ushort_t buf[8];
        #pragma unroll
        for (int e = 7; e >= 0; --e) {
            int i = base + seg * 8 + e;
            int2 p = bxy[i];
            int dy = abs(p.x - cy), dx = abs(p.y - cx);
            float a = lr * E[dy] * E[dx];
            buf[e] = f2bf(a * s);
            s *= (1.0f - a);
        }
        *reinterpret_cast<uint4*>(&coefT[(size_t)c * B_ + base + seg * 8]) =
            *reinterpret_cast<uint4*>(buf);
    }
}

// update GEMM via bf16 MFMA, single-buffer gl_lds staging, XCD-swizzled grid
__global__ __launch_bounds__(256) void k_update(const ushort_t* __restrict__ coefT, const ushort_t* __restrict__ xhT,
                                                const float* __restrict__ T, const float* __restrict__ w0,
                                                float* __restrict__ out) {
    __shared__ __align__(16) ushort_t As[64 * 64];
    __shared__ __align__(16) ushort_t Bs[64 * 64];
    const int tid = threadIdx.x;
    int orig = blockIdx.y * gridDim.x + blockIdx.x;
    int wgid = xcd_swz(orig, 4 * 157);
    const int d0 = (wgid & 3) * 64;
    const int c0 = (wgid >> 2) * 64;
    const int wid = tid >> 6, lane = tid & 63;
    const int wc = wid >> 1, wd = wid & 1;
    const int g4 = lane >> 4, l16 = lane & 15;

    f32x4 acc[2][2] = {};

    for (int k0 = 0; k0 < B_; k0 += 64) {
        if (k0) __syncthreads();
        #pragma unroll
        for (int r = 0; r < 2; ++r) {
            int f = tid + r * 256;        // [0,512): 64 rows x 8 16B-units
            int row = f >> 3, u = f & 7;
            int ug = (u ^ (row & 7)) * 8;
            int cc = c0 + row; if (cc > NC - 1) cc = NC - 1;
            gl_lds16(&coefT[(size_t)cc * B_ + k0 + ug], &As[(f & ~63) * 8]);
            gl_lds16(&xhT[(size_t)(d0 + row) * B_ + k0 + ug], &Bs[(f & ~63) * 8]);
        }
        __syncthreads();
        #pragma unroll
        for (int kh = 0; kh < 2; ++kh) {
            bf16x8 af[2], bfr[2];
            int ubase = kh * 4 + g4;
            #pragma unroll
            for (int fm = 0; fm < 2; ++fm) {
                int rowa = wc * 32 + fm * 16 + l16;
                af[fm] = *reinterpret_cast<const bf16x8*>(&As[rowa * 64 + ((ubase ^ (rowa & 7)) * 8)]);
                int rowb = wd * 32 + fm * 16 + l16;
                bfr[fm] = *reinterpret_cast<const bf16x8*>(&Bs[rowb * 64 + ((ubase ^ (rowb & 7)) * 8)]);
            }
            #pragma unroll
            for (int fm = 0; fm < 2; ++fm)
                #pragma unroll
                for (int fn = 0; fn < 2; ++fn)
                    acc[fm][fn] = __builtin_amdgcn_mfma_f32_16x16x32_bf16(af[fm], bfr[fn], acc[fm][fn], 0, 0, 0);
        }
    }

    #pragma unroll
    for (int fm = 0; fm < 2; ++fm) {
        #pragma unroll
        for (int r = 0; r < 4; ++r) {
            int c = c0 + wc * 32 + fm * 16 + g4 * 4 + r;
            if (c < NC) {
                float t = T[c];
                #pragma unroll
                for (int fn = 0; fn < 2; ++fn) {
                    int d = d0 + wd * 32 + fn * 16 + l16;
                    out[(size_t)c * D_ + d] = fmaf(t, w0[(size_t)c * D_ + d], acc[fm][fn][r]);
                }
            }
        }
    }
}

// ---------- tiny-ws fallback path ----------
__global__ void k_initfix(ull* packed_fix) {
    int i = blockIdx.x * 256 + threadIdx.x;
    if (i < B_) packed_fix[i] = ~0ull;
}
__global__ __launch_bounds__(256) void k_exact_bmu(const float* __restrict__ x, const float* __restrict__ w,
                                                   ull* __restrict__ packed_fix) {
    int b = blockIdx.x;
    int wid = threadIdx.x >> 6, lane = threadIdx.x & 63;
    float4 xv = *reinterpret_cast<const float4*>(&x[(size_t)b * D_ + lane * 4]);
    ull best = ~0ull;
    for (int c = wid; c < NC; c += 4) {
        float4 wv = *reinterpret_cast<const float4*>(&w[(size_t)c * D_ + lane * 4]);
        float p = wv.x * (wv.x - 2.0f * xv.x) + wv.y * (wv.y - 2.0f * xv.y)
                + wv.z * (wv.z - 2.0f * xv.z) + wv.w * (wv.w - 2.0f * xv.w);
        #pragma unroll
        for (int off = 32; off; off >>= 1) p += __shfl_xor(p, off);
        if (lane == 0) {
            ull pk = ((ull)fkey(p) << 32) | (unsigned)c;
            best = pk < best ? pk : best;
        }
    }
    if (lane == 0) atomicMin(&packed_fix[b], best);
}
__global__ void k_decode_force(const ull* __restrict__ packed_fix, float2* __restrict__ xy) {
    int i = blockIdx.x * 256 + threadIdx.x;
    if (i < B_) {
        int c = (int)(unsigned)(packed_fix[i] & 0xffffffffull);
        xy[i] = make_float2((float)(c / W_), (float)(c % W_));
    }
}
__global__ __launch_bounds__(256) void k_update_fallback(const float* __restrict__ x, const float* __restrict__ w0,
                                                         const float2* __restrict__ xy, const int* ep, const int* tp,
                                                         float* __restrict__ out) {
    int c = blockIdx.x;
    int d = threadIdx.x;
    float cyf = (float)(c / W_), cxf = (float)(c % W_);
    float lr, inv2r2;
    decay_params(ep, tp, lr, inv2r2);
    float acc = w0[(size_t)c * D_ + d];
    for (int i = 0; i < B_; ++i) {
        float2 p = xy[i];
        float dy = p.x - cyf, dx = p.y - cxf;
        float a = lr * __expf(-(dy * dy + dx * dx) * inv2r2);
        acc = fmaf(a, x[(size_t)i * D_ + d] - acc, acc);
    }
    out[(size_t)c * D_ + d] = acc;
}

extern "C" void kernel_launch(void* const* d_in, const int* in_sizes, int n_in,
                              void* d_out, int out_size, void* d_ws, size_t ws_size,
                              hipStream_t stream) {
    const float* x = (const float*)d_in[0];
    const float* w = (const float*)d_in[1];
    const int* ep = (const int*)d_in[2];
    const int* tp = (const int*)d_in[3];
    float* out = (float*)d_out;

    char* ws = (char*)d_ws;
    ull* packed_fix = (ull*)(ws + 8192);             // 8KB    @ 8K
    int2* bxy       = (int2*)(ws + 16384);           // 8KB    @ 16K
    float2* xyf     = (float2*)(ws + 16384);         // (fallback alias)
    float* T        = (float*)(ws + 24576);          // 40KB   @ 24K
    float* wnorm    = (float*)(ws + 65536);          // 40.5KB @ 64K
    ushort_t* xhT   = (ushort_t*)(ws + 131072);      // 512KB  @ 128K
    __half* xh      = (__half*)(ws + 655360);        // 512KB
    __half* wh      = (__half*)(ws + 1179648);       // 5.12MB
    ushort_t* coefT = (ushort_t*)(ws + 6553600);     // 20.48MB
    ull* pkt        = (ull*)(ws + 27262976);         // 1024*160*8 = 1.31MB -> ends 28573696
    int* doneCnt    = (int*)(ws + 28573696);         // 4KB
    size_t required = 28573696 + 4096;               // ~28.6MB

    if (ws_size >= required) {
        k_prep<<<NC / 4 + 64, 256, 0, stream>>>(w, x, wh, wnorm, xh, xhT);
        k_scores_mfma<<<dim3(8, NT), 512, 0, stream>>>(wh, xh, wnorm, pkt, packed_fix, doneCnt);
        k_bmu<<<dim3(MAXC, B_), 256, 0, stream>>>(pkt, x, w, packed_fix, doneCnt, bxy);
        k_scan<<<(NC * 8 + 255) / 256, 256, 0, stream>>>(bxy, ep, tp, coefT, T);
        k_update<<<dim3(4, 157), 256, 0, stream>>>(coefT, xhT, T, w, out);
    } else {
        k_initfix<<<4, 256, 0, stream>>>(packed_fix);
        k_exact_bmu<<<B_, 256, 0, stream>>>(x, w, packed_fix);
        k_decode_force<<<4, 256, 0, stream>>>(packed_fix, xyf);
        k_update_fallback<<<NC, 256, 0, stream>>>(x, w, xyf, ep, tp, out);
    }
}

// Round 12
// 143.140 us; speedup vs baseline: 1.3961x; 1.3961x over previous
//
#include <hip/hip_runtime.h>
#include <hip/hip_fp16.h>

typedef unsigned long long ull;
typedef unsigned short ushort_t;
typedef unsigned int u32;
typedef short bf16x8 __attribute__((ext_vector_type(8)));
typedef _Float16 f16x8 __attribute__((ext_vector_type(8)));
typedef float f32x4 __attribute__((ext_vector_type(4)));

#define NC 10000   // H*W cells
#define D_ 256     // input dim
#define B_ 1024    // batch
#define W_ 100     // grid width
#define NT 79      // score c-tiles (128 cells each)
#define PKS 160    // pkt row stride in ull
#define TAU 0.10f  // >= 2*eps_score for fp16-input MFMA scores (proven R7/R9/R10)
#define MAXC 16    // parallel exact-path blocks per sample

// async global->LDS, 16B per lane; LDS dest = wave-uniform base + lane*16
__device__ __forceinline__ void gl_lds16(const void* g, void* l) {
    __builtin_amdgcn_global_load_lds(
        (const __attribute__((address_space(1))) u32*)g,
        (__attribute__((address_space(3))) u32*)l,
        16, 0, 0);
}

// bijective XCD-chunk swizzle (m204)
__device__ __forceinline__ int xcd_swz(int orig, int nwg) {
    int q = nwg >> 3, r = nwg & 7;
    int xcd = orig & 7, off = orig >> 3;
    return (xcd < r ? xcd * (q + 1) : r * (q + 1) + (xcd - r) * q) + off;
}

// monotonic float -> sortable uint mapping
__device__ __forceinline__ unsigned fkey(float f) {
    unsigned u = __float_as_uint(f);
    return (u & 0x80000000u) ? ~u : (u | 0x80000000u);
}
__device__ __forceinline__ float unfkey(unsigned k) {
    unsigned u = (k & 0x80000000u) ? (k ^ 0x80000000u) : ~k;
    return __uint_as_float(u);
}

// exact RNE float -> bf16 bits
__device__ __forceinline__ ushort_t f2bf(float f) {
    unsigned u = __float_as_uint(f);
    unsigned r = (u + 0x7fffu + ((u >> 16) & 1u)) >> 16;
    return (ushort_t)r;
}

__device__ __forceinline__ void decay_params(const int* ep, const int* tp, float& lr, float& inv2r2) {
    double decay = 1.0 - (double)(*ep) / (double)(*tp);
    lr = (float)(0.5 * decay);
    float radius = (float)(50.0 * decay);
    inv2r2 = 1.0f / (2.0f * radius * radius);
}

// sorted-pair merge: (a1,a2) <- two smallest of {a1,a2,c1,c2}  (a1<=a2, c1<=c2)
__device__ __forceinline__ void merge2(ull& a1, ull& a2, ull c1, ull c2) {
    ull m1 = a1 < c1 ? a1 : c1;
    ull hi = a1 < c1 ? c1 : a1;
    ull lo2 = a2 < c2 ? a2 : c2;
    a2 = hi < lo2 ? hi : lo2;
    a1 = m1;
}

// fused prep: blocks [0,2500) = w -> wh fp16 + wnorm; blocks [2500,2564) = x -> xh fp16 + xhT bf16
// block 0 also zeroes the per-column done counters (ordered before k_scores by kernel boundary)
__global__ __launch_bounds__(256) void k_prep(const float* __restrict__ w, const float* __restrict__ x,
                                              __half* __restrict__ wh, float* __restrict__ wnorm,
                                              __half* __restrict__ xh, ushort_t* __restrict__ xhT,
                                              int* __restrict__ colDone) {
    int bid = blockIdx.x;
    int tid = threadIdx.x;
    if (bid == 0 && tid < 8) colDone[tid] = 0;
    if (bid < NC / 4) {
        int cell = bid * 4 + (tid >> 6);
        int lane = tid & 63;
        float4 v = *reinterpret_cast<const float4*>(&w[(size_t)cell * D_ + lane * 4]);
        float s = v.x * v.x + v.y * v.y + v.z * v.z + v.w * v.w;
        __half hb[4];
        float e[4] = {v.x, v.y, v.z, v.w};
        #pragma unroll
        for (int i = 0; i < 4; ++i) hb[i] = __float2half(e[i]);
        *reinterpret_cast<uint2*>(&wh[(size_t)cell * D_ + lane * 4]) = *reinterpret_cast<uint2*>(hb);
        #pragma unroll
        for (int off = 32; off; off >>= 1) s += __shfl_xor(s, off);
        if (lane == 0) wnorm[cell] = s;
    } else {
        __shared__ ushort_t tile[64][65];
        int idx = bid - NC / 4;
        int b0 = (idx & 15) * 64, d0 = (idx >> 4) * 64;
        #pragma unroll
        for (int r = 0; r < 16; ++r) {
            int f = r * 256 + tid;
            int i = f >> 6, j = f & 63;       // i = b-local, j = d-local
            float v = x[(size_t)(b0 + i) * D_ + d0 + j];
            xh[(size_t)(b0 + i) * D_ + d0 + j] = __float2half(v);
            tile[j][i] = f2bf(v);
        }
        __syncthreads();
        #pragma unroll
        for (int r = 0; r < 2; ++r) {
            int f = r * 256 + tid;            // [0,512): 64 d-rows x 8 units
            int row = f >> 3, u = f & 7;
            ushort_t v[8];
            #pragma unroll
            for (int e = 0; e < 8; ++e) v[e] = tile[row][u * 8 + e];
            *reinterpret_cast<uint4*>(&xhT[(size_t)(d0 + row) * B_ + b0 + u * 8]) =
                *reinterpret_cast<uint4*>(v);
        }
    }
}

// fp16 scores GEMM with fused per-tile (min1,min2) epilogue -> pkt[b][tile],
// PLUS fused cross-tile merge: the last of the NT blocks for a 128-sample column
// (device-scope ticket) merges all 79 pairs -> bxy / candN / candTiles.
__global__ __launch_bounds__(512) void k_scores_mfma(const __half* __restrict__ wh, const __half* __restrict__ xh,
                                                     const float* __restrict__ wnorm, ull* __restrict__ pkt,
                                                     int* __restrict__ colDone, int* __restrict__ candN,
                                                     int* __restrict__ candTiles, ull* __restrict__ packed_fix,
                                                     int* __restrict__ doneCnt, int2* __restrict__ bxy) {
    __shared__ __align__(16) __half As[128 * 64];  // cells x k  (16KB)
    __shared__ __align__(16) __half Bs[128 * 64];  // batch x k  (16KB)
    __shared__ int lastFlag;
    const int tid = threadIdx.x;
    int orig = blockIdx.y * gridDim.x + blockIdx.x;
    int wgid = xcd_swz(orig, 8 * NT);
    const int b0 = (wgid & 7) * 128;
    const int c0 = (wgid >> 3) * 128;
    const int tile = wgid >> 3;
    const int wid = tid >> 6, lane = tid & 63;
    const int wc = wid >> 2;           // 0..1 -> 64 cells
    const int wb = wid & 3;            // 0..3 -> 32 batch
    const int g4 = lane >> 4, l16 = lane & 15;

    f32x4 acc[4][2] = {};

    for (int k0 = 0; k0 < D_; k0 += 64) {
        if (k0) __syncthreads();
        #pragma unroll
        for (int r = 0; r < 2; ++r) {
            int f = tid + r * 512;        // [0,1024): 128 rows x 8 16B-units
            int row = f >> 3, u = f & 7;
            int ug = (u ^ (row & 7)) * 8;
            int cc = c0 + row; if (cc > NC - 1) cc = NC - 1;
            gl_lds16(&wh[(size_t)cc * D_ + k0 + ug], &As[(f & ~63) * 8]);
            gl_lds16(&xh[(size_t)(b0 + row) * D_ + k0 + ug], &Bs[(f & ~63) * 8]);
        }
        __syncthreads();
        #pragma unroll
        for (int kh = 0; kh < 2; ++kh) {
            int ubase = kh * 4 + g4;
            f16x8 bfr[2];
            #pragma unroll
            for (int fn = 0; fn < 2; ++fn) {
                int rowb = wb * 32 + fn * 16 + l16;
                bfr[fn] = *reinterpret_cast<const f16x8*>(&Bs[rowb * 64 + ((ubase ^ (rowb & 7)) * 8)]);
            }
            #pragma unroll
            for (int fm = 0; fm < 4; ++fm) {
                int rowa = wc * 64 + fm * 16 + l16;
                f16x8 af = *reinterpret_cast<const f16x8*>(&As[rowa * 64 + ((ubase ^ (rowa & 7)) * 8)]);
                #pragma unroll
                for (int fn = 0; fn < 2; ++fn)
                    acc[fm][fn] = __builtin_amdgcn_mfma_f32_16x16x32_f16(af, bfr[fn], acc[fm][fn], 0, 0, 0);
            }
        }
    }

    // per-lane (min1,min2) per fn over fm,r; phantom cells predicated out
    ull m1[2] = {~0ull, ~0ull}, m2[2] = {~0ull, ~0ull};
    #pragma unroll
    for (int fm = 0; fm < 4; ++fm) {
        int cb = c0 + wc * 64 + fm * 16 + g4 * 4;
        float4 wn4 = *reinterpret_cast<const float4*>(&wnorm[cb]);  // ws garbage ok for >=NC (masked)
        float wna[4] = {wn4.x, wn4.y, wn4.z, wn4.w};
        #pragma unroll
        for (int fn = 0; fn < 2; ++fn)
            #pragma unroll
            for (int r = 0; r < 4; ++r) {
                float s = wna[r] - 2.0f * acc[fm][fn][r];
                ull p = (cb + r < NC) ? (((ull)fkey(s) << 32) | (unsigned)(cb + r)) : ~0ull;
                merge2(m1[fn], m2[fn], p, ~0ull);
            }
    }
    #pragma unroll
    for (int fn = 0; fn < 2; ++fn) {
        #pragma unroll
        for (int off = 16; off <= 32; off <<= 1) {
            ull o1 = __shfl_xor(m1[fn], off), o2 = __shfl_xor(m2[fn], off);
            merge2(m1[fn], m2[fn], o1, o2);
        }
    }
    __syncthreads();                   // all MFMA LDS reads done before As reuse
    ull* sm1 = (ull*)&As[0];           // [2][128]
    ull* sm2 = sm1 + 256;
    if (g4 == 0) {
        #pragma unroll
        for (int fn = 0; fn < 2; ++fn) {
            int bl = wb * 32 + fn * 16 + l16;
            sm1[wc * 128 + bl] = m1[fn];
            sm2[wc * 128 + bl] = m2[fn];
        }
    }
    __syncthreads();
    if (tid < 128) {
        ull a1 = sm1[tid], a2 = sm2[tid];
        merge2(a1, a2, sm1[128 + tid], sm2[128 + tid]);
        size_t base = (size_t)(b0 + tid) * PKS + tile * 2;
        pkt[base] = a1;
        pkt[base + 1] = a2;
    }

    // ---- column ticket: last of the NT blocks for this b0 merges all tiles ----
    __syncthreads();
    if (tid == 0) {
        __threadfence();               // release: this block's pkt stores (L2 writeback)
        lastFlag = (atomicAdd(&colDone[b0 >> 7], 1) == NT - 1);
    }
    __syncthreads();
    if (!lastFlag) return;             // uniform
    __threadfence();                   // acquire: other blocks' pkt stores

    {
        int s4 = tid >> 2, q = tid & 3;    // 4 threads per sample
        int b = b0 + s4;
        int gb = lane & ~3;
        ull a1 = ~0ull, a2 = ~0ull;
        #pragma unroll 4
        for (int t = q; t < NT; t += 4) {
            size_t base = (size_t)b * PKS + t * 2;
            merge2(a1, a2, pkt[base], pkt[base + 1]);
        }
        #pragma unroll
        for (int off = 1; off <= 2; off <<= 1) {
            ull o1 = __shfl_xor(a1, off), o2 = __shfl_xor(a2, off);
            merge2(a1, a2, o1, o2);
        }
        float f1 = unfkey((unsigned)(a1 >> 32));
        float f2 = unfkey((unsigned)(a2 >> 32));
        int c1 = (int)(unsigned)(a1 & 0xffffffffull);
        if (f2 - f1 >= TAU) {
            if (q == 0) {
                candN[b] = 0;
                bxy[b] = make_int2(c1 / W_, c1 % W_);
            }
        } else {
            float thr = f1 + TAU;
            int cnt = 0;
            #pragma unroll 4
            for (int t = q; t < NT; t += 4)
                if (unfkey((unsigned)(pkt[(size_t)b * PKS + t * 2] >> 32)) <= thr) ++cnt;
            int c0q = __shfl(cnt, gb + 0), c1q = __shfl(cnt, gb + 1);
            int c2q = __shfl(cnt, gb + 2), c3q = __shfl(cnt, gb + 3);
            int pre = (q > 0 ? c0q : 0) + (q > 1 ? c1q : 0) + (q > 2 ? c2q : 0);
            int idx = b * (NT + 1) + pre;
            for (int t = q; t < NT; t += 4)
                if (unfkey((unsigned)(pkt[(size_t)b * PKS + t * 2] >> 32)) <= thr) candTiles[idx++] = t;
            if (q == 0) {
                candN[b] = c0q + c1q + c2q + c3q;   // >= 1
                doneCnt[b] = 0;
                packed_fix[b] = ~0ull;
                bxy[b] = make_int2(c1 / W_, c1 % W_);  // provisional; k_bmu2 overwrites
            }
        }
    }
}

// exact path: grid (B_, MAXC); block (b,j) exact-fp32 min over candidate tiles j, j+MAXC, ...
// wave-per-cell coalesced dots; one u64 atomicMin per block; last-done block decodes -> bxy
__global__ __launch_bounds__(256) void k_bmu2(const int* __restrict__ candN, const int* __restrict__ candTiles,
                                              const float* __restrict__ x, const float* __restrict__ w,
                                              ull* __restrict__ packed_fix, int* __restrict__ doneCnt,
                                              int2* __restrict__ bxy) {
    int b = blockIdx.x, j = blockIdx.y;
    int n = candN[b];
    if (j >= n) return;
    int target = n < MAXC ? n : MAXC;
    __shared__ ull sb[4];
    int tid = threadIdx.x, lane = tid & 63, wv = tid >> 6;
    float4 xv = *reinterpret_cast<const float4*>(&x[(size_t)b * D_ + lane * 4]);
    ull best = ~0ull;
    for (int ci = j; ci < n; ci += MAXC) {
        int t = candTiles[b * (NT + 1) + ci];
        #pragma unroll 4
        for (int i = wv; i < 128; i += 4) {   // 4 waves x unroll-4 independent streams
            int c = t * 128 + i;
            if (c < NC) {
                float4 wv4 = *reinterpret_cast<const float4*>(&w[(size_t)c * D_ + lane * 4]);
                float p = wv4.x * (wv4.x - 2.0f * xv.x) + wv4.y * (wv4.y - 2.0f * xv.y)
                        + wv4.z * (wv4.z - 2.0f * xv.z) + wv4.w * (wv4.w - 2.0f * xv.w);
                #pragma unroll
                for (int off = 32; off; off >>= 1) p += __shfl_xor(p, off);
                if (lane == 0) {
                    ull pk = ((ull)fkey(p) << 32) | (unsigned)c;
                    best = pk < best ? pk : best;
                }
            }
        }
    }
    if (lane == 0) sb[wv] = best;
    __syncthreads();
    if (tid == 0) {
        best = sb[0];
        #pragma unroll
        for (int k = 1; k < 4; ++k) best = sb[k] < best ? sb[k] : best;
        atomicMin(&packed_fix[b], best);
        __threadfence();
        int old = atomicAdd(&doneCnt[b], 1);
        if (old == target - 1) {       // last block: all mins visible
            __threadfence();
            ull fin = packed_fix[b];
            int c = (int)(unsigned)(fin & 0xffffffffull);
            bxy[b] = make_int2(c / W_, c % W_);
        }
    }
}

// chunked 2-pass suffix scan with separable-Gaussian LDS table
__global__ __launch_bounds__(256) void k_scan(const int2* __restrict__ bxy, const int* __restrict__ ep,
                                              const int* __restrict__ tp, ushort_t* __restrict__ coefT,
                                              float* __restrict__ T) {
    __shared__ float E[W_];
    float lr, inv2r2;
    decay_params(ep, tp, lr, inv2r2);
    if (threadIdx.x < W_) {
        float d = (float)threadIdx.x;
        E[threadIdx.x] = __expf(-d * d * inv2r2);
    }
    __syncthreads();

    int g = blockIdx.x * 256 + threadIdx.x;
    int c = g >> 3, t = g & 7;
    if (c >= NC) return;
    int cy = c / W_, cx = c % W_;
    int base = t * 128;

    float P = 1.0f;
    for (int i = base; i < base + 128; ++i) {
        int2 p = bxy[i];
        int dy = abs(p.x - cy), dx = abs(p.y - cx);
        float a = lr * E[dy] * E[dx];
        P *= (1.0f - a);
    }
    int gbase = (threadIdx.x & 63) & ~7;
    float M = 1.0f;
    #pragma unroll
    for (int k = 1; k < 8; ++k) {
        float pk = __shfl(P, gbase + k, 64);
        if (k > t) M *= pk;
    }
    if (t == 0) T[c] = M * P;

    float s = M;
    for (int seg = 15; seg >= 0; --seg) {
        ushort_t buf[8];
        #pragma unroll
        for (int e = 7; e >= 0; --e) {
            int i = base + seg * 8 + e;
            int2 p = bxy[i];
            int dy = abs(p.x - cy), dx = abs(p.y - cx);
            float a = lr * E[dy] * E[dx];
            buf[e] = f2bf(a * s);
            s *= (1.0f - a);
        }
        *reinterpret_cast<uint4*>(&coefT[(size_t)c * B_ + base + seg * 8]) =
            *reinterpret_cast<uint4*>(buf);
    }
}

// update GEMM via bf16 MFMA, single-buffer gl_lds staging, XCD-swizzled grid
__global__ __launch_bounds__(256) void k_update(const ushort_t* __restrict__ coefT, const ushort_t* __restrict__ xhT,
                                                const float* __restrict__ T, const float* __restrict__ w0,
                                                float* __restrict__ out) {
    __shared__ __align__(16) ushort_t As[64 * 64];
    __shared__ __align__(16) ushort_t Bs[64 * 64];
    const int tid = threadIdx.x;
    int orig = blockIdx.y * gridDim.x + blockIdx.x;
    int wgid = xcd_swz(orig, 4 * 157);
    const int d0 = (wgid & 3) * 64;
    const int c0 = (wgid >> 2) * 64;
    const int wid = tid >> 6, lane = tid & 63;
    const int wc = wid >> 1, wd = wid & 1;
    const int g4 = lane >> 4, l16 = lane & 15;

    f32x4 acc[2][2] = {};

    for (int k0 = 0; k0 < B_; k0 += 64) {
        if (k0) __syncthreads();
        #pragma unroll
        for (int r = 0; r < 2; ++r) {
            int f = tid + r * 256;        // [0,512): 64 rows x 8 16B-units
            int row = f >> 3, u = f & 7;
            int ug = (u ^ (row & 7)) * 8;
            int cc = c0 + row; if (cc > NC - 1) cc = NC - 1;
            gl_lds16(&coefT[(size_t)cc * B_ + k0 + ug], &As[(f & ~63) * 8]);
            gl_lds16(&xhT[(size_t)(d0 + row) * B_ + k0 + ug], &Bs[(f & ~63) * 8]);
        }
        __syncthreads();
        #pragma unroll
        for (int kh = 0; kh < 2; ++kh) {
            bf16x8 af[2], bfr[2];
            int ubase = kh * 4 + g4;
            #pragma unroll
            for (int fm = 0; fm < 2; ++fm) {
                int rowa = wc * 32 + fm * 16 + l16;
                af[fm] = *reinterpret_cast<const bf16x8*>(&As[rowa * 64 + ((ubase ^ (rowa & 7)) * 8)]);
                int rowb = wd * 32 + fm * 16 + l16;
                bfr[fm] = *reinterpret_cast<const bf16x8*>(&Bs[rowb * 64 + ((ubase ^ (rowb & 7)) * 8)]);
            }
            #pragma unroll
            for (int fm = 0; fm < 2; ++fm)
                #pragma unroll
                for (int fn = 0; fn < 2; ++fn)
                    acc[fm][fn] = __builtin_amdgcn_mfma_f32_16x16x32_bf16(af[fm], bfr[fn], acc[fm][fn], 0, 0, 0);
        }
    }

    #pragma unroll
    for (int fm = 0; fm < 2; ++fm) {
        #pragma unroll
        for (int r = 0; r < 4; ++r) {
            int c = c0 + wc * 32 + fm * 16 + g4 * 4 + r;
            if (c < NC) {
                float t = T[c];
                #pragma unroll
                for (int fn = 0; fn < 2; ++fn) {
                    int d = d0 + wd * 32 + fn * 16 + l16;
                    out[(size_t)c * D_ + d] = fmaf(t, w0[(size_t)c * D_ + d], acc[fm][fn][r]);
                }
            }
        }
    }
}

// ---------- tiny-ws fallback path ----------
__global__ void k_initfix(ull* packed_fix) {
    int i = blockIdx.x * 256 + threadIdx.x;
    if (i < B_) packed_fix[i] = ~0ull;
}
__global__ __launch_bounds__(256) void k_exact_bmu(const float* __restrict__ x, const float* __restrict__ w,
                                                   ull* __restrict__ packed_fix) {
    int b = blockIdx.x;
    int wid = threadIdx.x >> 6, lane = threadIdx.x & 63;
    float4 xv = *reinterpret_cast<const float4*>(&x[(size_t)b * D_ + lane * 4]);
    ull best = ~0ull;
    for (int c = wid; c < NC; c += 4) {
        float4 wv = *reinterpret_cast<const float4*>(&w[(size_t)c * D_ + lane * 4]);
        float p = wv.x * (wv.x - 2.0f * xv.x) + wv.y * (wv.y - 2.0f * xv.y)
                + wv.z * (wv.z - 2.0f * xv.z) + wv.w * (wv.w - 2.0f * xv.w);
        #pragma unroll
        for (int off = 32; off; off >>= 1) p += __shfl_xor(p, off);
        if (lane == 0) {
            ull pk = ((ull)fkey(p) << 32) | (unsigned)c;
            best = pk < best ? pk : best;
        }
    }
    if (lane == 0) atomicMin(&packed_fix[b], best);
}
__global__ void k_decode_force(const ull* __restrict__ packed_fix, float2* __restrict__ xy) {
    int i = blockIdx.x * 256 + threadIdx.x;
    if (i < B_) {
        int c = (int)(unsigned)(packed_fix[i] & 0xffffffffull);
        xy[i] = make_float2((float)(c / W_), (float)(c % W_));
    }
}
__global__ __launch_bounds__(256) void k_update_fallback(const float* __restrict__ x, const float* __restrict__ w0,
                                                         const float2* __restrict__ xy, const int* ep, const int* tp,
                                                         float* __restrict__ out) {
    int c = blockIdx.x;
    int d = threadIdx.x;
    float cyf = (float)(c / W_), cxf = (float)(c % W_);
    float lr, inv2r2;
    decay_params(ep, tp, lr, inv2r2);
    float acc = w0[(size_t)c * D_ + d];
    for (int i = 0; i < B_; ++i) {
        float2 p = xy[i];
        float dy = p.x - cyf, dx = p.y - cxf;
        float a = lr * __expf(-(dy * dy + dx * dx) * inv2r2);
        acc = fmaf(a, x[(size_t)i * D_ + d] - acc, acc);
    }
    out[(size_t)c * D_ + d] = acc;
}

extern "C" void kernel_launch(void* const* d_in, const int* in_sizes, int n_in,
                              void* d_out, int out_size, void* d_ws, size_t ws_size,
                              hipStream_t stream) {
    const float* x = (const float*)d_in[0];
    const float* w = (const float*)d_in[1];
    const int* ep = (const int*)d_in[2];
    const int* tp = (const int*)d_in[3];
    float* out = (float*)d_out;

    char* ws = (char*)d_ws;
    ull* packed_fix = (ull*)(ws + 8192);             // 8KB    @ 8K
    int2* bxy       = (int2*)(ws + 16384);           // 8KB    @ 16K
    float2* xyf     = (float2*)(ws + 16384);         // (fallback alias)
    float* T        = (float*)(ws + 24576);          // 40KB   @ 24K
    float* wnorm    = (float*)(ws + 65536);          // 40.5KB @ 64K
    ushort_t* xhT   = (ushort_t*)(ws + 131072);      // 512KB  @ 128K
    __half* xh      = (__half*)(ws + 655360);        // 512KB
    __half* wh      = (__half*)(ws + 1179648);       // 5.12MB
    ushort_t* coefT = (ushort_t*)(ws + 6553600);     // 20.48MB
    ull* pkt        = (ull*)(ws + 27262976);         // 1.31MB -> ends 28573696
    int* doneCnt    = (int*)(ws + 28573696);         // 4KB
    int* candN      = (int*)(ws + 28577792);         // 4KB
    int* candTiles  = (int*)(ws + 28581888);         // 1024*80*4 = 320KB -> ends 28909568
    int* colDone    = (int*)(ws + 28909568);         // 32B (pad 4KB)
    size_t required = 28909568 + 4096;               // ~28.9MB

    if (ws_size >= required) {
        k_prep<<<NC / 4 + 64, 256, 0, stream>>>(w, x, wh, wnorm, xh, xhT, colDone);
        k_scores_mfma<<<dim3(8, NT), 512, 0, stream>>>(wh, xh, wnorm, pkt, colDone,
                                                       candN, candTiles, packed_fix, doneCnt, bxy);
        k_bmu2<<<dim3(B_, MAXC), 256, 0, stream>>>(candN, candTiles, x, w, packed_fix, doneCnt, bxy);
        k_scan<<<(NC * 8 + 255) / 256, 256, 0, stream>>>(bxy, ep, tp, coefT, T);
        k_update<<<dim3(4, 157), 256, 0, stream>>>(coefT, xhT, T, w, out);
    } else {
        k_initfix<<<4, 256, 0, stream>>>(packed_fix);
        k_exact_bmu<<<B_, 256, 0, stream>>>(x, w, packed_fix);
        k_decode_force<<<4, 256, 0, stream>>>(packed_fix, xyf);
        k_update_fallback<<<NC, 256, 0, stream>>>(x, w, xyf, ep, tp, out);
    }
}

// Round 13
// 86.398 us; speedup vs baseline: 2.3130x; 1.6568x over previous
//
#include <hip/hip_runtime.h>
#include <hip/hip_fp16.h>

typedef unsigned long long ull;
typedef unsigned short ushort_t;
typedef unsigned int u32;
typedef short bf16x8 __attribute__((ext_vector_type(8)));
typedef _Float16 f16x8 __attribute__((ext_vector_type(8)));
typedef float f32x4 __attribute__((ext_vector_type(4)));

#define NC 10000   // H*W cells
#define D_ 256     // input dim
#define B_ 1024    // batch
#define W_ 100     // grid width
#define NT 79      // score c-tiles
#define LD 10240   // padded row stride for h
#define FIXMARGIN 0.06f  // >= 2*eps_score(fp16 mfma scores) — proven R5
#define SHORTCAP 128

// async global->LDS, 16B per lane; LDS dest = wave-uniform base + lane*16
__device__ __forceinline__ void gl_lds16(const void* g, void* l) {
    __builtin_amdgcn_global_load_lds(
        (const __attribute__((address_space(1))) u32*)g,
        (__attribute__((address_space(3))) u32*)l,
        16, 0, 0);
}

// bijective XCD-chunk swizzle (m204)
__device__ __forceinline__ int xcd_swz(int orig, int nwg) {
    int q = nwg >> 3, r = nwg & 7;
    int xcd = orig & 7, off = orig >> 3;
    return (xcd < r ? xcd * (q + 1) : r * (q + 1) + (xcd - r) * q) + off;
}

// monotonic float -> sortable uint mapping
__device__ __forceinline__ unsigned fkey(float f) {
    unsigned u = __float_as_uint(f);
    return (u & 0x80000000u) ? ~u : (u | 0x80000000u);
}
__device__ __forceinline__ float unfkey(unsigned k) {
    unsigned u = (k & 0x80000000u) ? (k ^ 0x80000000u) : ~k;
    return __uint_as_float(u);
}

// exact RNE float -> bf16 bits
__device__ __forceinline__ ushort_t f2bf(float f) {
    unsigned u = __float_as_uint(f);
    unsigned r = (u + 0x7fffu + ((u >> 16) & 1u)) >> 16;
    return (ushort_t)r;
}

__device__ __forceinline__ void decay_params(const int* ep, const int* tp, float& lr, float& inv2r2) {
    double decay = 1.0 - (double)(*ep) / (double)(*tp);
    lr = (float)(0.5 * decay);
    float radius = (float)(50.0 * decay);
    inv2r2 = 1.0f / (2.0f * radius * radius);
}

// fused prep: blocks [0,2500) = w -> wh fp16 + wnorm; [2500,2564) = x -> xh fp16 + xhT bf16;
// block 2564 = init pk1 (~0) + wnorm phantom pad (+inf) for the last c-tile's clamped rows
__global__ __launch_bounds__(256) void k_prep(const float* __restrict__ w, const float* __restrict__ x,
                                              __half* __restrict__ wh, float* __restrict__ wnorm,
                                              __half* __restrict__ xh, ushort_t* __restrict__ xhT,
                                              ull* __restrict__ pk1) {
    int bid = blockIdx.x;
    int tid = threadIdx.x;
    if (bid < NC / 4) {
        int cell = bid * 4 + (tid >> 6);
        int lane = tid & 63;
        float4 v = *reinterpret_cast<const float4*>(&w[(size_t)cell * D_ + lane * 4]);
        float s = v.x * v.x + v.y * v.y + v.z * v.z + v.w * v.w;
        __half hb[4];
        float e[4] = {v.x, v.y, v.z, v.w};
        #pragma unroll
        for (int i = 0; i < 4; ++i) hb[i] = __float2half(e[i]);
        *reinterpret_cast<uint2*>(&wh[(size_t)cell * D_ + lane * 4]) = *reinterpret_cast<uint2*>(hb);
        #pragma unroll
        for (int off = 32; off; off >>= 1) s += __shfl_xor(s, off);
        if (lane == 0) wnorm[cell] = s;
    } else if (bid < NC / 4 + 64) {
        __shared__ ushort_t tile[64][65];
        int idx = bid - NC / 4;
        int b0 = (idx & 15) * 64, d0 = (idx >> 4) * 64;
        #pragma unroll
        for (int r = 0; r < 16; ++r) {
            int f = r * 256 + tid;
            int i = f >> 6, j = f & 63;       // i = b-local, j = d-local
            float v = x[(size_t)(b0 + i) * D_ + d0 + j];
            xh[(size_t)(b0 + i) * D_ + d0 + j] = __float2half(v);
            tile[j][i] = f2bf(v);
        }
        __syncthreads();
        #pragma unroll
        for (int r = 0; r < 2; ++r) {
            int f = r * 256 + tid;            // [0,512): 64 d-rows x 8 units
            int row = f >> 3, u = f & 7;
            ushort_t v[8];
            #pragma unroll
            for (int e = 0; e < 8; ++e) v[e] = tile[row][u * 8 + e];
            *reinterpret_cast<uint4*>(&xhT[(size_t)(d0 + row) * B_ + b0 + u * 8]) =
                *reinterpret_cast<uint4*>(v);
        }
    } else {
        #pragma unroll
        for (int k = 0; k < 4; ++k) pk1[tid * 4 + k] = ~0ull;
        if (tid < 128) wnorm[NC + tid] = __builtin_inff();
    }
}

// fp16 scores GEMM (R5-proven): h[b][c] = fp16(xh.wh) + fused per-sample min1 atomicMin
// tile 128 cells x 128 batch, BK=64, 8 waves (2 cell x 4 batch), single-buffer staging
__global__ __launch_bounds__(512) void k_scores_mfma(const __half* __restrict__ wh, const __half* __restrict__ xh,
                                                     const float* __restrict__ wnorm, __half* __restrict__ h,
                                                     ull* __restrict__ pk1) {
    __shared__ __align__(16) __half As[128 * 64];  // cells x k  (16KB)
    __shared__ __align__(16) __half Bs[128 * 64];  // batch x k  (16KB)
    const int tid = threadIdx.x;
    int orig = blockIdx.y * gridDim.x + blockIdx.x;
    int wgid = xcd_swz(orig, 8 * NT);
    const int b0 = (wgid & 7) * 128;
    const int c0 = (wgid >> 3) * 128;
    const int wid = tid >> 6, lane = tid & 63;
    const int wc = wid >> 2;           // 0..1 -> 64 cells
    const int wb = wid & 3;            // 0..3 -> 32 batch
    const int g4 = lane >> 4, l16 = lane & 15;

    f32x4 acc[4][2] = {};

    for (int k0 = 0; k0 < D_; k0 += 64) {
        if (k0) __syncthreads();
        #pragma unroll
        for (int r = 0; r < 2; ++r) {
            int f = tid + r * 512;        // [0,1024): 128 rows x 8 16B-units
            int row = f >> 3, u = f & 7;
            int ug = (u ^ (row & 7)) * 8;
            int cc = c0 + row; if (cc > NC - 1) cc = NC - 1;
            gl_lds16(&wh[(size_t)cc * D_ + k0 + ug], &As[(f & ~63) * 8]);
            gl_lds16(&xh[(size_t)(b0 + row) * D_ + k0 + ug], &Bs[(f & ~63) * 8]);
        }
        __syncthreads();
        #pragma unroll
        for (int kh = 0; kh < 2; ++kh) {
            int ubase = kh * 4 + g4;
            f16x8 bfr[2];
            #pragma unroll
            for (int fn = 0; fn < 2; ++fn) {
                int rowb = wb * 32 + fn * 16 + l16;
                bfr[fn] = *reinterpret_cast<const f16x8*>(&Bs[rowb * 64 + ((ubase ^ (rowb & 7)) * 8)]);
            }
            #pragma unroll
            for (int fm = 0; fm < 4; ++fm) {
                int rowa = wc * 64 + fm * 16 + l16;
                f16x8 af = *reinterpret_cast<const f16x8*>(&As[rowa * 64 + ((ubase ^ (rowa & 7)) * 8)]);
                #pragma unroll
                for (int fn = 0; fn < 2; ++fn)
                    acc[fm][fn] = __builtin_amdgcn_mfma_f32_16x16x32_f16(af, bfr[fn], acc[fm][fn], 0, 0, 0);
            }
        }
    }

    // store h (dot, fp16) — k_fix shortlists from it (pad region c>=NC never read)
    #pragma unroll
    for (int fm = 0; fm < 4; ++fm) {
        int cb = c0 + wc * 64 + fm * 16 + g4 * 4;
        #pragma unroll
        for (int fn = 0; fn < 2; ++fn) {
            int b = b0 + wb * 32 + fn * 16 + l16;
            __half hv[4];
            #pragma unroll
            for (int r = 0; r < 4; ++r) hv[r] = __float2half(acc[fm][fn][r]);
            *reinterpret_cast<uint2*>(&h[(size_t)b * LD + cb]) = *reinterpret_cast<uint2*>(hv);
        }
    }

    // fused min1: per-lane reduce over fm,r; shfl across g4; one atomic per column
    // (wnorm[cb>=NC] = +inf pad -> phantom cells never win)
    ull best[2] = {~0ull, ~0ull};
    #pragma unroll
    for (int fm = 0; fm < 4; ++fm) {
        int cb = c0 + wc * 64 + fm * 16 + g4 * 4;
        float4 wn4 = *reinterpret_cast<const float4*>(&wnorm[cb]);
        float wna[4] = {wn4.x, wn4.y, wn4.z, wn4.w};
        #pragma unroll
        for (int fn = 0; fn < 2; ++fn)
            #pragma unroll
            for (int r = 0; r < 4; ++r) {
                float s = wna[r] - 2.0f * acc[fm][fn][r];
                ull p = ((ull)fkey(s) << 32) | (unsigned)(cb + r);
                if (p < best[fn]) best[fn] = p;
            }
    }
    #pragma unroll
    for (int fn = 0; fn < 2; ++fn) {
        ull o = __shfl_xor(best[fn], 16); best[fn] = o < best[fn] ? o : best[fn];
        o = __shfl_xor(best[fn], 32);     best[fn] = o < best[fn] ? o : best[fn];
    }
    if (g4 == 0) {
        atomicMin(&pk1[b0 + wb * 32 + l16], best[0]);
        atomicMin(&pk1[b0 + wb * 32 + 16 + l16], best[1]);
    }
}

// always-on fix (R5-proven): shortlist cells within FIXMARGIN of approx min,
// exact fp32 dots, block-local reduce, write bxy directly
__global__ __launch_bounds__(256) void k_fix(const __half* __restrict__ h, const float* __restrict__ wnorm,
                                             const float* __restrict__ x, const float* __restrict__ w,
                                             const ull* __restrict__ pk1, int2* __restrict__ bxy) {
    __shared__ int cnt;
    __shared__ int cand[SHORTCAP];
    __shared__ ull sbest[4];
    int b = blockIdx.x, tid = threadIdx.x;
    if (tid == 0) cnt = 0;
    __syncthreads();
    float thr = unfkey((unsigned)(pk1[b] >> 32)) + FIXMARGIN;
    for (int ch = 0; ch < 10; ++ch) {
        int c = ch * 1024 + tid * 4;
        if (c < NC) {
            __half hv[4];
            *reinterpret_cast<uint2*>(hv) = *reinterpret_cast<const uint2*>(&h[(size_t)b * LD + c]);
            float4 wn = *reinterpret_cast<const float4*>(&wnorm[c]);
            float we[4] = {wn.x, wn.y, wn.z, wn.w};
            #pragma unroll
            for (int e = 0; e < 4; ++e) {
                float s = we[e] - 2.0f * (float)hv[e];
                if (s <= thr) {
                    int p = atomicAdd(&cnt, 1);
                    if (p < SHORTCAP) cand[p] = c + e;
                }
            }
        }
    }
    __syncthreads();
    int n = cnt;
    int wid = tid >> 6, lane = tid & 63;
    float4 xv = *reinterpret_cast<const float4*>(&x[(size_t)b * D_ + lane * 4]);
    ull best = ~0ull;
    if (n <= SHORTCAP) {
        for (int i = wid; i < n; i += 4) {
            int c = cand[i];
            float4 wv = *reinterpret_cast<const float4*>(&w[(size_t)c * D_ + lane * 4]);
            float p = wv.x * (wv.x - 2.0f * xv.x) + wv.y * (wv.y - 2.0f * xv.y)
                    + wv.z * (wv.z - 2.0f * xv.z) + wv.w * (wv.w - 2.0f * xv.w);
            #pragma unroll
            for (int off = 32; off; off >>= 1) p += __shfl_xor(p, off);
            if (lane == 0) {
                ull pk = ((ull)fkey(p) << 32) | (unsigned)c;
                best = pk < best ? pk : best;
            }
        }
    } else {  // pathological overflow: full exact scan (deterministic, ~never taken)
        for (int c = wid; c < NC; c += 4) {
            float4 wv = *reinterpret_cast<const float4*>(&w[(size_t)c * D_ + lane * 4]);
            float p = wv.x * (wv.x - 2.0f * xv.x) + wv.y * (wv.y - 2.0f * xv.y)
                    + wv.z * (wv.z - 2.0f * xv.z) + wv.w * (wv.w - 2.0f * xv.w);
            #pragma unroll
            for (int off = 32; off; off >>= 1) p += __shfl_xor(p, off);
            if (lane == 0) {
                ull pk = ((ull)fkey(p) << 32) | (unsigned)c;
                best = pk < best ? pk : best;
            }
        }
    }
    if (lane == 0) sbest[wid] = best;
    __syncthreads();
    if (tid == 0) {
        ull bb = sbest[0];
        #pragma unroll
        for (int k = 1; k < 4; ++k) bb = sbest[k] < bb ? sbest[k] : bb;
        int c = (int)(unsigned)(bb & 0xffffffffull);
        bxy[b] = make_int2(c / W_, c % W_);
    }
}

// chunked 2-pass suffix scan with separable-Gaussian LDS table
__global__ __launch_bounds__(256) void k_scan(const int2* __restrict__ bxy, const int* __restrict__ ep,
                                              const int* __restrict__ tp, ushort_t* __restrict__ coefT,
                                              float* __restrict__ T) {
    __shared__ float E[W_];
    float lr, inv2r2;
    decay_params(ep, tp, lr, inv2r2);
    if (threadIdx.x < W_) {
        float d = (float)threadIdx.x;
        E[threadIdx.x] = __expf(-d * d * inv2r2);
    }
    __syncthreads();

    int g = blockIdx.x * 256 + threadIdx.x;
    int c = g >> 3, t = g & 7;
    if (c >= NC) return;
    int cy = c / W_, cx = c % W_;
    int base = t * 128;

    float P = 1.0f;
    for (int i = base; i < base + 128; ++i) {
        int2 p = bxy[i];
        int dy = abs(p.x - cy), dx = abs(p.y - cx);
        float a = lr * E[dy] * E[dx];
        P *= (1.0f - a);
    }
    int gbase = (threadIdx.x & 63) & ~7;
    float M = 1.0f;
    #pragma unroll
    for (int k = 1; k < 8; ++k) {
        float pk = __shfl(P, gbase + k, 64);
        if (k > t) M *= pk;
    }
    if (t == 0) T[c] = M * P;

    float s = M;
    for (int seg = 15; seg >= 0; --seg) {
        ushort_t buf[8];
        #pragma unroll
        for (int e = 7; e >= 0; --e) {
            int i = base + seg * 8 + e;
            int2 p = bxy[i];
            int dy = abs(p.x - cy), dx = abs(p.y - cx);
            float a = lr * E[dy] * E[dx];
            buf[e] = f2bf(a * s);
            s *= (1.0f - a);
        }
        *reinterpret_cast<uint4*>(&coefT[(size_t)c * B_ + base + seg * 8]) =
            *reinterpret_cast<uint4*>(buf);
    }
}

// update GEMM via bf16 MFMA, single-buffer gl_lds staging, XCD-swizzled grid
__global__ __launch_bounds__(256) void k_update(const ushort_t* __restrict__ coefT, const ushort_t* __restrict__ xhT,
                                                const float* __restrict__ T, const float* __restrict__ w0,
                                                float* __restrict__ out) {
    __shared__ __align__(16) ushort_t As[64 * 64];
    __shared__ __align__(16) ushort_t Bs[64 * 64];
    const int tid = threadIdx.x;
    int orig = blockIdx.y * gridDim.x + blockIdx.x;
    int wgid = xcd_swz(orig, 4 * 157);
    const int d0 = (wgid & 3) * 64;
    const int c0 = (wgid >> 2) * 64;
    const int wid = tid >> 6, lane = tid & 63;
    const int wc = wid >> 1, wd = wid & 1;
    const int g4 = lane >> 4, l16 = lane & 15;

    f32x4 acc[2][2] = {};

    for (int k0 = 0; k0 < B_; k0 += 64) {
        if (k0) __syncthreads();
        #pragma unroll
        for (int r = 0; r < 2; ++r) {
            int f = tid + r * 256;        // [0,512): 64 rows x 8 16B-units
            int row = f >> 3, u = f & 7;
            int ug = (u ^ (row & 7)) * 8;
            int cc = c0 + row; if (cc > NC - 1) cc = NC - 1;
            gl_lds16(&coefT[(size_t)cc * B_ + k0 + ug], &As[(f & ~63) * 8]);
            gl_lds16(&xhT[(size_t)(d0 + row) * B_ + k0 + ug], &Bs[(f & ~63) * 8]);
        }
        __syncthreads();
        #pragma unroll
        for (int kh = 0; kh < 2; ++kh) {
            bf16x8 af[2], bfr[2];
            int ubase = kh * 4 + g4;
            #pragma unroll
            for (int fm = 0; fm < 2; ++fm) {
                int rowa = wc * 32 + fm * 16 + l16;
                af[fm] = *reinterpret_cast<const bf16x8*>(&As[rowa * 64 + ((ubase ^ (rowa & 7)) * 8)]);
                int rowb = wd * 32 + fm * 16 + l16;
                bfr[fm] = *reinterpret_cast<const bf16x8*>(&Bs[rowb * 64 + ((ubase ^ (rowb & 7)) * 8)]);
            }
            #pragma unroll
            for (int fm = 0; fm < 2; ++fm)
                #pragma unroll
                for (int fn = 0; fn < 2; ++fn)
                    acc[fm][fn] = __builtin_amdgcn_mfma_f32_16x16x32_bf16(af[fm], bfr[fn], acc[fm][fn], 0, 0, 0);
        }
    }

    #pragma unroll
    for (int fm = 0; fm < 2; ++fm) {
        #pragma unroll
        for (int r = 0; r < 4; ++r) {
            int c = c0 + wc * 32 + fm * 16 + g4 * 4 + r;
            if (c < NC) {
                float t = T[c];
                #pragma unroll
                for (int fn = 0; fn < 2; ++fn) {
                    int d = d0 + wd * 32 + fn * 16 + l16;
                    out[(size_t)c * D_ + d] = fmaf(t, w0[(size_t)c * D_ + d], acc[fm][fn][r]);
                }
            }
        }
    }
}

// ---------- tiny-ws fallback path ----------
__global__ void k_initfix(ull* packed_fix) {
    int i = blockIdx.x * 256 + threadIdx.x;
    if (i < B_) packed_fix[i] = ~0ull;
}
__global__ __launch_bounds__(256) void k_exact_bmu(const float* __restrict__ x, const float* __restrict__ w,
                                                   ull* __restrict__ packed_fix) {
    int b = blockIdx.x;
    int wid = threadIdx.x >> 6, lane = threadIdx.x & 63;
    float4 xv = *reinterpret_cast<const float4*>(&x[(size_t)b * D_ + lane * 4]);
    ull best = ~0ull;
    for (int c = wid; c < NC; c += 4) {
        float4 wv = *reinterpret_cast<const float4*>(&w[(size_t)c * D_ + lane * 4]);
        float p = wv.x * (wv.x - 2.0f * xv.x) + wv.y * (wv.y - 2.0f * xv.y)
                + wv.z * (wv.z - 2.0f * xv.z) + wv.w * (wv.w - 2.0f * xv.w);
        #pragma unroll
        for (int off = 32; off; off >>= 1) p += __shfl_xor(p, off);
        if (lane == 0) {
            ull pk = ((ull)fkey(p) << 32) | (unsigned)c;
            best = pk < best ? pk : best;
        }
    }
    if (lane == 0) atomicMin(&packed_fix[b], best);
}
__global__ void k_decode_force(const ull* __restrict__ packed_fix, float2* __restrict__ xy) {
    int i = blockIdx.x * 256 + threadIdx.x;
    if (i < B_) {
        int c = (int)(unsigned)(packed_fix[i] & 0xffffffffull);
        xy[i] = make_float2((float)(c / W_), (float)(c % W_));
    }
}
__global__ __launch_bounds__(256) void k_update_fallback(const float* __restrict__ x, const float* __restrict__ w0,
                                                         const float2* __restrict__ xy, const int* ep, const int* tp,
                                                         float* __restrict__ out) {
    int c = blockIdx.x;
    int d = threadIdx.x;
    float cyf = (float)(c / W_), cxf = (float)(c % W_);
    float lr, inv2r2;
    decay_params(ep, tp, lr, inv2r2);
    float acc = w0[(size_t)c * D_ + d];
    for (int i = 0; i < B_; ++i) {
        float2 p = xy[i];
        float dy = p.x - cyf, dx = p.y - cxf;
        float a = lr * __expf(-(dy * dy + dx * dx) * inv2r2);
        acc = fmaf(a, x[(size_t)i * D_ + d] - acc, acc);
    }
    out[(size_t)c * D_ + d] = acc;
}

extern "C" void kernel_launch(void* const* d_in, const int* in_sizes, int n_in,
                              void* d_out, int out_size, void* d_ws, size_t ws_size,
                              hipStream_t stream) {
    const float* x = (const float*)d_in[0];
    const float* w = (const float*)d_in[1];
    const int* ep = (const int*)d_in[2];
    const int* tp = (const int*)d_in[3];
    float* out = (float*)d_out;

    char* ws = (char*)d_ws;
    ull* pk1        = (ull*)ws;                      // 8KB    @ 0
    int2* bxy       = (int2*)(ws + 16384);           // 8KB    @ 16K
    float2* xyf     = (float2*)(ws + 16384);         // (fallback alias)
    float* T        = (float*)(ws + 24576);          // 40KB   @ 24K
    float* wnorm    = (float*)(ws + 65536);          // 40.5KB @ 64K (incl +128 pad)
    ushort_t* xhT   = (ushort_t*)(ws + 131072);      // 512KB  @ 128K
    __half* xh      = (__half*)(ws + 655360);        // 512KB
    __half* wh      = (__half*)(ws + 1179648);       // 5.12MB
    ushort_t* coefT = (ushort_t*)(ws + 6553600);     // 20.48MB
    __half* h       = (__half*)(ws + 27262976);      // 20.97MB
    size_t required = 27262976 + (size_t)B_ * LD * 2;  // ~48.2MB

    if (ws_size >= required) {
        k_prep<<<NC / 4 + 64 + 1, 256, 0, stream>>>(w, x, wh, wnorm, xh, xhT, pk1);
        k_scores_mfma<<<dim3(8, NT), 512, 0, stream>>>(wh, xh, wnorm, h, pk1);
        k_fix<<<B_, 256, 0, stream>>>(h, wnorm, x, w, pk1, bxy);
        k_scan<<<(NC * 8 + 255) / 256, 256, 0, stream>>>(bxy, ep, tp, coefT, T);
        k_update<<<dim3(4, 157), 256, 0, stream>>>(coefT, xhT, T, w, out);
    } else {
        k_initfix<<<4, 256, 0, stream>>>(pk1);
        k_exact_bmu<<<B_, 256, 0, stream>>>(x, w, pk1);
        k_decode_force<<<4, 256, 0, stream>>>(pk1, xyf);
        k_update_fallback<<<NC, 256, 0, stream>>>(x, w, xyf, ep, tp, out);
    }
}

// Round 14
// 86.250 us; speedup vs baseline: 2.3170x; 1.0017x over previous
//
#include <hip/hip_runtime.h>
#include <hip/hip_fp16.h>

typedef unsigned long long ull;
typedef unsigned short ushort_t;
typedef unsigned int u32;
typedef short bf16x8 __attribute__((ext_vector_type(8)));
typedef _Float16 f16x8 __attribute__((ext_vector_type(8)));
typedef float f32x4 __attribute__((ext_vector_type(4)));

#define NC 10000   // H*W cells
#define D_ 256     // input dim
#define B_ 1024    // batch
#define W_ 100     // grid width
#define NT 79      // score c-tiles
#define LD 10240   // padded row stride for h
#define FIXMARGIN 0.06f  // >= 2*eps_score(fp16 mfma scores) — proven R5/R13
#define SHORTCAP 128

// async global->LDS, 16B per lane; LDS dest = wave-uniform base + lane*16
__device__ __forceinline__ void gl_lds16(const void* g, void* l) {
    __builtin_amdgcn_global_load_lds(
        (const __attribute__((address_space(1))) u32*)g,
        (__attribute__((address_space(3))) u32*)l,
        16, 0, 0);
}

// bijective XCD-chunk swizzle (m204)
__device__ __forceinline__ int xcd_swz(int orig, int nwg) {
    int q = nwg >> 3, r = nwg & 7;
    int xcd = orig & 7, off = orig >> 3;
    return (xcd < r ? xcd * (q + 1) : r * (q + 1) + (xcd - r) * q) + off;
}

// monotonic float -> sortable uint mapping
__device__ __forceinline__ unsigned fkey(float f) {
    unsigned u = __float_as_uint(f);
    return (u & 0x80000000u) ? ~u : (u | 0x80000000u);
}
__device__ __forceinline__ float unfkey(unsigned k) {
    unsigned u = (k & 0x80000000u) ? (k ^ 0x80000000u) : ~k;
    return __uint_as_float(u);
}

// exact RNE float -> bf16 bits
__device__ __forceinline__ ushort_t f2bf(float f) {
    unsigned u = __float_as_uint(f);
    unsigned r = (u + 0x7fffu + ((u >> 16) & 1u)) >> 16;
    return (ushort_t)r;
}

__device__ __forceinline__ void decay_params(const int* ep, const int* tp, float& lr, float& inv2r2) {
    double decay = 1.0 - (double)(*ep) / (double)(*tp);
    lr = (float)(0.5 * decay);
    float radius = (float)(50.0 * decay);
    inv2r2 = 1.0f / (2.0f * radius * radius);
}

// fused prep: blocks [0,2500) = w -> wh fp16 + wnorm; [2500,2564) = x -> xh fp16 + xhT bf16;
// block 2564 = init pk1 (~0) + wnorm phantom pad (+inf)
__global__ __launch_bounds__(256) void k_prep(const float* __restrict__ w, const float* __restrict__ x,
                                              __half* __restrict__ wh, float* __restrict__ wnorm,
                                              __half* __restrict__ xh, ushort_t* __restrict__ xhT,
                                              ull* __restrict__ pk1) {
    int bid = blockIdx.x;
    int tid = threadIdx.x;
    if (bid < NC / 4) {
        int cell = bid * 4 + (tid >> 6);
        int lane = tid & 63;
        float4 v = *reinterpret_cast<const float4*>(&w[(size_t)cell * D_ + lane * 4]);
        float s = v.x * v.x + v.y * v.y + v.z * v.z + v.w * v.w;
        __half hb[4];
        float e[4] = {v.x, v.y, v.z, v.w};
        #pragma unroll
        for (int i = 0; i < 4; ++i) hb[i] = __float2half(e[i]);
        *reinterpret_cast<uint2*>(&wh[(size_t)cell * D_ + lane * 4]) = *reinterpret_cast<uint2*>(hb);
        #pragma unroll
        for (int off = 32; off; off >>= 1) s += __shfl_xor(s, off);
        if (lane == 0) wnorm[cell] = s;
    } else if (bid < NC / 4 + 64) {
        __shared__ ushort_t tile[64][65];
        int idx = bid - NC / 4;
        int b0 = (idx & 15) * 64, d0 = (idx >> 4) * 64;
        #pragma unroll
        for (int r = 0; r < 16; ++r) {
            int f = r * 256 + tid;
            int i = f >> 6, j = f & 63;       // i = b-local, j = d-local
            float v = x[(size_t)(b0 + i) * D_ + d0 + j];
            xh[(size_t)(b0 + i) * D_ + d0 + j] = __float2half(v);
            tile[j][i] = f2bf(v);
        }
        __syncthreads();
        #pragma unroll
        for (int r = 0; r < 2; ++r) {
            int f = r * 256 + tid;            // [0,512): 64 d-rows x 8 units
            int row = f >> 3, u = f & 7;
            ushort_t v[8];
            #pragma unroll
            for (int e = 0; e < 8; ++e) v[e] = tile[row][u * 8 + e];
            *reinterpret_cast<uint4*>(&xhT[(size_t)(d0 + row) * B_ + b0 + u * 8]) =
                *reinterpret_cast<uint4*>(v);
        }
    } else {
        #pragma unroll
        for (int k = 0; k < 4; ++k) pk1[tid * 4 + k] = ~0ull;
        if (tid < 128) wnorm[NC + tid] = __builtin_inff();
    }
}

// fp16 scores GEMM: h[b][c] = fp16(xh.wh) + fused per-sample min1 atomicMin
// tile 128 cells x 128 batch, BK=128 (2 K-iterations, half the barrier drains),
// 8 waves (2 cell x 4 batch), single-buffer staging, 16-unit XOR swizzle
__global__ __launch_bounds__(512) void k_scores_mfma(const __half* __restrict__ wh, const __half* __restrict__ xh,
                                                     const float* __restrict__ wnorm, __half* __restrict__ h,
                                                     ull* __restrict__ pk1) {
    __shared__ __align__(16) __half As[128 * 128];  // cells x k  (32KB)
    __shared__ __align__(16) __half Bs[128 * 128];  // batch x k  (32KB)
    const int tid = threadIdx.x;
    int orig = blockIdx.y * gridDim.x + blockIdx.x;
    int wgid = xcd_swz(orig, 8 * NT);
    const int b0 = (wgid & 7) * 128;
    const int c0 = (wgid >> 3) * 128;
    const int wid = tid >> 6, lane = tid & 63;
    const int wc = wid >> 2;           // 0..1 -> 64 cells
    const int wb = wid & 3;            // 0..3 -> 32 batch
    const int g4 = lane >> 4, l16 = lane & 15;

    f32x4 acc[4][2] = {};

    for (int k0 = 0; k0 < D_; k0 += 128) {
        if (k0) __syncthreads();
        #pragma unroll
        for (int r = 0; r < 4; ++r) {
            int f = tid + r * 512;        // [0,2048): 128 rows x 16 16B-units
            int row = f >> 4, u = f & 15;
            int ug = (u ^ (row & 15)) * 8;
            int cc = c0 + row; if (cc > NC - 1) cc = NC - 1;
            gl_lds16(&wh[(size_t)cc * D_ + k0 + ug], &As[(f & ~63) * 8]);
            gl_lds16(&xh[(size_t)(b0 + row) * D_ + k0 + ug], &Bs[(f & ~63) * 8]);
        }
        __syncthreads();
        #pragma unroll
        for (int kh = 0; kh < 4; ++kh) {
            int ubase = kh * 4 + g4;
            f16x8 bfr[2];
            #pragma unroll
            for (int fn = 0; fn < 2; ++fn) {
                int rowb = wb * 32 + fn * 16 + l16;
                bfr[fn] = *reinterpret_cast<const f16x8*>(&Bs[rowb * 128 + ((ubase ^ (rowb & 15)) * 8)]);
            }
            #pragma unroll
            for (int fm = 0; fm < 4; ++fm) {
                int rowa = wc * 64 + fm * 16 + l16;
                f16x8 af = *reinterpret_cast<const f16x8*>(&As[rowa * 128 + ((ubase ^ (rowa & 15)) * 8)]);
                #pragma unroll
                for (int fn = 0; fn < 2; ++fn)
                    acc[fm][fn] = __builtin_amdgcn_mfma_f32_16x16x32_f16(af, bfr[fn], acc[fm][fn], 0, 0, 0);
            }
        }
    }

    // store h (dot, fp16) — k_fix shortlists from it (pad region c>=NC never read)
    #pragma unroll
    for (int fm = 0; fm < 4; ++fm) {
        int cb = c0 + wc * 64 + fm * 16 + g4 * 4;
        #pragma unroll
        for (int fn = 0; fn < 2; ++fn) {
            int b = b0 + wb * 32 + fn * 16 + l16;
            __half hv[4];
            #pragma unroll
            for (int r = 0; r < 4; ++r) hv[r] = __float2half(acc[fm][fn][r]);
            *reinterpret_cast<uint2*>(&h[(size_t)b * LD + cb]) = *reinterpret_cast<uint2*>(hv);
        }
    }

    // fused min1: per-lane reduce over fm,r; shfl across g4; one atomic per column
    // (wnorm[cb>=NC] = +inf pad -> phantom cells never win)
    ull best[2] = {~0ull, ~0ull};
    #pragma unroll
    for (int fm = 0; fm < 4; ++fm) {
        int cb = c0 + wc * 64 + fm * 16 + g4 * 4;
        float4 wn4 = *reinterpret_cast<const float4*>(&wnorm[cb]);
        float wna[4] = {wn4.x, wn4.y, wn4.z, wn4.w};
        #pragma unroll
        for (int fn = 0; fn < 2; ++fn)
            #pragma unroll
            for (int r = 0; r < 4; ++r) {
                float s = wna[r] - 2.0f * acc[fm][fn][r];
                ull p = ((ull)fkey(s) << 32) | (unsigned)(cb + r);
                if (p < best[fn]) best[fn] = p;
            }
    }
    #pragma unroll
    for (int fn = 0; fn < 2; ++fn) {
        ull o = __shfl_xor(best[fn], 16); best[fn] = o < best[fn] ? o : best[fn];
        o = __shfl_xor(best[fn], 32);     best[fn] = o < best[fn] ? o : best[fn];
    }
    if (g4 == 0) {
        atomicMin(&pk1[b0 + wb * 32 + l16], best[0]);
        atomicMin(&pk1[b0 + wb * 32 + 16 + l16], best[1]);
    }
}

// always-on fix (R5/R13-proven): shortlist cells within FIXMARGIN of approx min,
// exact fp32 dots, block-local reduce, write bxy directly
__global__ __launch_bounds__(256) void k_fix(const __half* __restrict__ h, const float* __restrict__ wnorm,
                                             const float* __restrict__ x, const float* __restrict__ w,
                                             const ull* __restrict__ pk1, int2* __restrict__ bxy) {
    __shared__ int cnt;
    __shared__ int cand[SHORTCAP];
    __shared__ ull sbest[4];
    int b = blockIdx.x, tid = threadIdx.x;
    if (tid == 0) cnt = 0;
    __syncthreads();
    float thr = unfkey((unsigned)(pk1[b] >> 32)) + FIXMARGIN;
    for (int ch = 0; ch < 10; ++ch) {
        int c = ch * 1024 + tid * 4;
        if (c < NC) {
            __half hv[4];
            *reinterpret_cast<uint2*>(hv) = *reinterpret_cast<const uint2*>(&h[(size_t)b * LD + c]);
            float4 wn = *reinterpret_cast<const float4*>(&wnorm[c]);
            float we[4] = {wn.x, wn.y, wn.z, wn.w};
            #pragma unroll
            for (int e = 0; e < 4; ++e) {
                float s = we[e] - 2.0f * (float)hv[e];
                if (s <= thr) {
                    int p = atomicAdd(&cnt, 1);
                    if (p < SHORTCAP) cand[p] = c + e;
                }
            }
        }
    }
    __syncthreads();
    int n = cnt;
    int wid = tid >> 6, lane = tid & 63;
    float4 xv = *reinterpret_cast<const float4*>(&x[(size_t)b * D_ + lane * 4]);
    ull best = ~0ull;
    if (n <= SHORTCAP) {
        for (int i = wid; i < n; i += 4) {
            int c = cand[i];
            float4 wv = *reinterpret_cast<const float4*>(&w[(size_t)c * D_ + lane * 4]);
            float p = wv.x * (wv.x - 2.0f * xv.x) + wv.y * (wv.y - 2.0f * xv.y)
                    + wv.z * (wv.z - 2.0f * xv.z) + wv.w * (wv.w - 2.0f * xv.w);
            #pragma unroll
            for (int off = 32; off; off >>= 1) p += __shfl_xor(p, off);
            if (lane == 0) {
                ull pk = ((ull)fkey(p) << 32) | (unsigned)c;
                best = pk < best ? pk : best;
            }
        }
    } else {  // pathological overflow: full exact scan (deterministic, ~never taken)
        for (int c = wid; c < NC; c += 4) {
            float4 wv = *reinterpret_cast<const float4*>(&w[(size_t)c * D_ + lane * 4]);
            float p = wv.x * (wv.x - 2.0f * xv.x) + wv.y * (wv.y - 2.0f * xv.y)
                    + wv.z * (wv.z - 2.0f * xv.z) + wv.w * (wv.w - 2.0f * xv.w);
            #pragma unroll
            for (int off = 32; off; off >>= 1) p += __shfl_xor(p, off);
            if (lane == 0) {
                ull pk = ((ull)fkey(p) << 32) | (unsigned)c;
                best = pk < best ? pk : best;
            }
        }
    }
    if (lane == 0) sbest[wid] = best;
    __syncthreads();
    if (tid == 0) {
        ull bb = sbest[0];
        #pragma unroll
        for (int k = 1; k < 4; ++k) bb = sbest[k] < bb ? sbest[k] : bb;
        int c = (int)(unsigned)(bb & 0xffffffffull);
        bxy[b] = make_int2(c / W_, c % W_);
    }
}

// chunked 2-pass suffix scan with separable-Gaussian LDS table
__global__ __launch_bounds__(256) void k_scan(const int2* __restrict__ bxy, const int* __restrict__ ep,
                                              const int* __restrict__ tp, ushort_t* __restrict__ coefT,
                                              float* __restrict__ T) {
    __shared__ float E[W_];
    float lr, inv2r2;
    decay_params(ep, tp, lr, inv2r2);
    if (threadIdx.x < W_) {
        float d = (float)threadIdx.x;
        E[threadIdx.x] = __expf(-d * d * inv2r2);
    }
    __syncthreads();

    int g = blockIdx.x * 256 + threadIdx.x;
    int c = g >> 3, t = g & 7;
    if (c >= NC) return;
    int cy = c / W_, cx = c % W_;
    int base = t * 128;

    float P = 1.0f;
    for (int i = base; i < base + 128; ++i) {
        int2 p = bxy[i];
        int dy = abs(p.x - cy), dx = abs(p.y - cx);
        float a = lr * E[dy] * E[dx];
        P *= (1.0f - a);
    }
    int gbase = (threadIdx.x & 63) & ~7;
    float M = 1.0f;
    #pragma unroll
    for (int k = 1; k < 8; ++k) {
        float pk = __shfl(P, gbase + k, 64);
        if (k > t) M *= pk;
    }
    if (t == 0) T[c] = M * P;

    float s = M;
    for (int seg = 15; seg >= 0; --seg) {
        ushort_t buf[8];
        #pragma unroll
        for (int e = 7; e >= 0; --e) {
            int i = base + seg * 8 + e;
            int2 p = bxy[i];
            int dy = abs(p.x - cy), dx = abs(p.y - cx);
            float a = lr * E[dy] * E[dx];
            buf[e] = f2bf(a * s);
            s *= (1.0f - a);
        }
        *reinterpret_cast<uint4*>(&coefT[(size_t)c * B_ + base + seg * 8]) =
            *reinterpret_cast<uint4*>(buf);
    }
}

// update GEMM via bf16 MFMA, BK=128 (8 K-iterations, half the barrier drains),
// single-buffer gl_lds staging, 16-unit XOR swizzle, XCD-swizzled grid
__global__ __launch_bounds__(256) void k_update(const ushort_t* __restrict__ coefT, const ushort_t* __restrict__ xhT,
                                                const float* __restrict__ T, const float* __restrict__ w0,
                                                float* __restrict__ out) {
    __shared__ __align__(16) ushort_t As[64 * 128];  // 16KB
    __shared__ __align__(16) ushort_t Bs[64 * 128];  // 16KB
    const int tid = threadIdx.x;
    int orig = blockIdx.y * gridDim.x + blockIdx.x;
    int wgid = xcd_swz(orig, 4 * 157);
    const int d0 = (wgid & 3) * 64;
    const int c0 = (wgid >> 2) * 64;
    const int wid = tid >> 6, lane = tid & 63;
    const int wc = wid >> 1, wd = wid & 1;
    const int g4 = lane >> 4, l16 = lane & 15;

    f32x4 acc[2][2] = {};

    for (int k0 = 0; k0 < B_; k0 += 128) {
        if (k0) __syncthreads();
        #pragma unroll
        for (int r = 0; r < 4; ++r) {
            int f = tid + r * 256;        // [0,1024): 64 rows x 16 16B-units
            int row = f >> 4, u = f & 15;
            int ug = (u ^ (row & 15)) * 8;
            int cc = c0 + row; if (cc > NC - 1) cc = NC - 1;
            gl_lds16(&coefT[(size_t)cc * B_ + k0 + ug], &As[(f & ~63) * 8]);
            gl_lds16(&xhT[(size_t)(d0 + row) * B_ + k0 + ug], &Bs[(f & ~63) * 8]);
        }
        __syncthreads();
        #pragma unroll
        for (int kh = 0; kh < 4; ++kh) {
            bf16x8 af[2], bfr[2];
            int ubase = kh * 4 + g4;
            #pragma unroll
            for (int fm = 0; fm < 2; ++fm) {
                int rowa = wc * 32 + fm * 16 + l16;
                af[fm] = *reinterpret_cast<const bf16x8*>(&As[rowa * 128 + ((ubase ^ (rowa & 15)) * 8)]);
                int rowb = wd * 32 + fm * 16 + l16;
                bfr[fm] = *reinterpret_cast<const bf16x8*>(&Bs[rowb * 128 + ((ubase ^ (rowb & 15)) * 8)]);
            }
            #pragma unroll
            for (int fm = 0; fm < 2; ++fm)
                #pragma unroll
                for (int fn = 0; fn < 2; ++fn)
                    acc[fm][fn] = __builtin_amdgcn_mfma_f32_16x16x32_bf16(af[fm], bfr[fn], acc[fm][fn], 0, 0, 0);
        }
    }

    #pragma unroll
    for (int fm = 0; fm < 2; ++fm) {
        #pragma unroll
        for (int r = 0; r < 4; ++r) {
            int c = c0 + wc * 32 + fm * 16 + g4 * 4 + r;
            if (c < NC) {
                float t = T[c];
                #pragma unroll
                for (int fn = 0; fn < 2; ++fn) {
                    int d = d0 + wd * 32 + fn * 16 + l16;
                    out[(size_t)c * D_ + d] = fmaf(t, w0[(size_t)c * D_ + d], acc[fm][fn][r]);
                }
            }
        }
    }
}

// ---------- tiny-ws fallback path ----------
__global__ void k_initfix(ull* packed_fix) {
    int i = blockIdx.x * 256 + threadIdx.x;
    if (i < B_) packed_fix[i] = ~0ull;
}
__global__ __launch_bounds__(256) void k_exact_bmu(const float* __restrict__ x, const float* __restrict__ w,
                                                   ull* __restrict__ packed_fix) {
    int b = blockIdx.x;
    int wid = threadIdx.x >> 6, lane = threadIdx.x & 63;
    float4 xv = *reinterpret_cast<const float4*>(&x[(size_t)b * D_ + lane * 4]);
    ull best = ~0ull;
    for (int c = wid; c < NC; c += 4) {
        float4 wv = *reinterpret_cast<const float4*>(&w[(size_t)c * D_ + lane * 4]);
        float p = wv.x * (wv.x - 2.0f * xv.x) + wv.y * (wv.y - 2.0f * xv.y)
                + wv.z * (wv.z - 2.0f * xv.z) + wv.w * (wv.w - 2.0f * xv.w);
        #pragma unroll
        for (int off = 32; off; off >>= 1) p += __shfl_xor(p, off);
        if (lane == 0) {
            ull pk = ((ull)fkey(p) << 32) | (unsigned)c;
            best = pk < best ? pk : best;
        }
    }
    if (lane == 0) atomicMin(&packed_fix[b], best);
}
__global__ void k_decode_force(const ull* __restrict__ packed_fix, float2* __restrict__ xy) {
    int i = blockIdx.x * 256 + threadIdx.x;
    if (i < B_) {
        int c = (int)(unsigned)(packed_fix[i] & 0xffffffffull);
        xy[i] = make_float2((float)(c / W_), (float)(c % W_));
    }
}
__global__ __launch_bounds__(256) void k_update_fallback(const float* __restrict__ x, const float* __restrict__ w0,
                                                         const float2* __restrict__ xy, const int* ep, const int* tp,
                                                         float* __restrict__ out) {
    int c = blockIdx.x;
    int d = threadIdx.x;
    float cyf = (float)(c / W_), cxf = (float)(c % W_);
    float lr, inv2r2;
    decay_params(ep, tp, lr, inv2r2);
    float acc = w0[(size_t)c * D_ + d];
    for (int i = 0; i < B_; ++i) {
        float2 p = xy[i];
        float dy = p.x - cyf, dx = p.y - cxf;
        float a = lr * __expf(-(dy * dy + dx * dx) * inv2r2);
        acc = fmaf(a, x[(size_t)i * D_ + d] - acc, acc);
    }
    out[(size_t)c * D_ + d] = acc;
}

extern "C" void kernel_launch(void* const* d_in, const int* in_sizes, int n_in,
                              void* d_out, int out_size, void* d_ws, size_t ws_size,
                              hipStream_t stream) {
    const float* x = (const float*)d_in[0];
    const float* w = (const float*)d_in[1];
    const int* ep = (const int*)d_in[2];
    const int* tp = (const int*)d_in[3];
    float* out = (float*)d_out;

    char* ws = (char*)d_ws;
    ull* pk1        = (ull*)ws;                      // 8KB    @ 0
    int2* bxy       = (int2*)(ws + 16384);           // 8KB    @ 16K
    float2* xyf     = (float2*)(ws + 16384);         // (fallback alias)
    float* T        = (float*)(ws + 24576);          // 40KB   @ 24K
    float* wnorm    = (float*)(ws + 65536);          // 40.5KB @ 64K (incl +128 pad)
    ushort_t* xhT   = (ushort_t*)(ws + 131072);      // 512KB  @ 128K
    __half* xh      = (__half*)(ws + 655360);        // 512KB
    __half* wh      = (__half*)(ws + 1179648);       // 5.12MB
    ushort_t* coefT = (ushort_t*)(ws + 6553600);     // 20.48MB
    __half* h       = (__half*)(ws + 27262976);      // 20.97MB
    size_t required = 27262976 + (size_t)B_ * LD * 2;  // ~48.2MB

    if (ws_size >= required) {
        k_prep<<<NC / 4 + 64 + 1, 256, 0, stream>>>(w, x, wh, wnorm, xh, xhT, pk1);
        k_scores_mfma<<<dim3(8, NT), 512, 0, stream>>>(wh, xh, wnorm, h, pk1);
        k_fix<<<B_, 256, 0, stream>>>(h, wnorm, x, w, pk1, bxy);
        k_scan<<<(NC * 8 + 255) / 256, 256, 0, stream>>>(bxy, ep, tp, coefT, T);
        k_update<<<dim3(4, 157), 256, 0, stream>>>(coefT, xhT, T, w, out);
    } else {
        k_initfix<<<4, 256, 0, stream>>>(pk1);
        k_exact_bmu<<<B_, 256, 0, stream>>>(x, w, pk1);
        k_decode_force<<<4, 256, 0, stream>>>(pk1, xyf);
        k_update_fallback<<<NC, 256, 0, stream>>>(x, w, xyf, ep, tp, out);
    }
}

// Round 15
// 85.323 us; speedup vs baseline: 2.3422x; 1.0109x over previous
//
#include <hip/hip_runtime.h>
#include <hip/hip_fp16.h>

typedef unsigned long long ull;
typedef unsigned short ushort_t;
typedef unsigned int u32;
typedef short bf16x8 __attribute__((ext_vector_type(8)));
typedef _Float16 f16x8 __attribute__((ext_vector_type(8)));
typedef float f32x4 __attribute__((ext_vector_type(4)));

#define NC 10000   // H*W cells
#define D_ 256     // input dim
#define B_ 1024    // batch
#define W_ 100     // grid width
#define NTC 157    // scores c-tiles (64 cells each), 157*64=10048
#define LD 10240   // padded row stride for h
#define FIXMARGIN 0.06f  // >= 2*eps_score(fp16 mfma scores) — proven R5/R13
#define SHORTCAP 128

// async global->LDS, 16B per lane; LDS dest = wave-uniform base + lane*16
__device__ __forceinline__ void gl_lds16(const void* g, void* l) {
    __builtin_amdgcn_global_load_lds(
        (const __attribute__((address_space(1))) u32*)g,
        (__attribute__((address_space(3))) u32*)l,
        16, 0, 0);
}

// bijective XCD-chunk swizzle (m204)
__device__ __forceinline__ int xcd_swz(int orig, int nwg) {
    int q = nwg >> 3, r = nwg & 7;
    int xcd = orig & 7, off = orig >> 3;
    return (xcd < r ? xcd * (q + 1) : r * (q + 1) + (xcd - r) * q) + off;
}

// monotonic float -> sortable uint mapping
__device__ __forceinline__ unsigned fkey(float f) {
    unsigned u = __float_as_uint(f);
    return (u & 0x80000000u) ? ~u : (u | 0x80000000u);
}
__device__ __forceinline__ float unfkey(unsigned k) {
    unsigned u = (k & 0x80000000u) ? (k ^ 0x80000000u) : ~k;
    return __uint_as_float(u);
}

// exact RNE float -> bf16 bits
__device__ __forceinline__ ushort_t f2bf(float f) {
    unsigned u = __float_as_uint(f);
    unsigned r = (u + 0x7fffu + ((u >> 16) & 1u)) >> 16;
    return (ushort_t)r;
}

__device__ __forceinline__ void decay_params(const int* ep, const int* tp, float& lr, float& inv2r2) {
    double decay = 1.0 - (double)(*ep) / (double)(*tp);
    lr = (float)(0.5 * decay);
    float radius = (float)(50.0 * decay);
    inv2r2 = 1.0f / (2.0f * radius * radius);
}

// fused prep: blocks [0,2500) = w -> wh fp16 + wnorm; [2500,2564) = x -> xh fp16 + xhT bf16;
// block 2564 = init pk1 (~0) + wnorm phantom pad (+inf)
__global__ __launch_bounds__(256) void k_prep(const float* __restrict__ w, const float* __restrict__ x,
                                              __half* __restrict__ wh, float* __restrict__ wnorm,
                                              __half* __restrict__ xh, ushort_t* __restrict__ xhT,
                                              ull* __restrict__ pk1) {
    int bid = blockIdx.x;
    int tid = threadIdx.x;
    if (bid < NC / 4) {
        int cell = bid * 4 + (tid >> 6);
        int lane = tid & 63;
        float4 v = *reinterpret_cast<const float4*>(&w[(size_t)cell * D_ + lane * 4]);
        float s = v.x * v.x + v.y * v.y + v.z * v.z + v.w * v.w;
        __half hb[4];
        float e[4] = {v.x, v.y, v.z, v.w};
        #pragma unroll
        for (int i = 0; i < 4; ++i) hb[i] = __float2half(e[i]);
        *reinterpret_cast<uint2*>(&wh[(size_t)cell * D_ + lane * 4]) = *reinterpret_cast<uint2*>(hb);
        #pragma unroll
        for (int off = 32; off; off >>= 1) s += __shfl_xor(s, off);
        if (lane == 0) wnorm[cell] = s;
    } else if (bid < NC / 4 + 64) {
        __shared__ ushort_t tile[64][65];
        int idx = bid - NC / 4;
        int b0 = (idx & 15) * 64, d0 = (idx >> 4) * 64;
        #pragma unroll
        for (int r = 0; r < 16; ++r) {
            int f = r * 256 + tid;
            int i = f >> 6, j = f & 63;       // i = b-local, j = d-local
            float v = x[(size_t)(b0 + i) * D_ + d0 + j];
            xh[(size_t)(b0 + i) * D_ + d0 + j] = __float2half(v);
            tile[j][i] = f2bf(v);
        }
        __syncthreads();
        #pragma unroll
        for (int r = 0; r < 2; ++r) {
            int f = r * 256 + tid;            // [0,512): 64 d-rows x 8 units
            int row = f >> 3, u = f & 7;
            ushort_t v[8];
            #pragma unroll
            for (int e = 0; e < 8; ++e) v[e] = tile[row][u * 8 + e];
            *reinterpret_cast<uint4*>(&xhT[(size_t)(d0 + row) * B_ + b0 + u * 8]) =
                *reinterpret_cast<uint4*>(v);
        }
    } else {
        #pragma unroll
        for (int k = 0; k < 4; ++k) pk1[tid * 4 + k] = ~0ull;
        if (tid < 128) wnorm[NC + tid] = __builtin_inff();
    }
}

// fp16 scores GEMM: h[b][c] = fp16(xh.wh) + fused per-sample min1 atomicMin
// tile 64 cells x 128 batch, BK=64, 8 waves (2 cell-halves x 4 batch-quarters),
// single-buffer staging — grid 1256 blocks (~4.9/CU) for latency hiding
__global__ __launch_bounds__(512) void k_scores_mfma(const __half* __restrict__ wh, const __half* __restrict__ xh,
                                                     const float* __restrict__ wnorm, __half* __restrict__ h,
                                                     ull* __restrict__ pk1) {
    __shared__ __align__(16) __half As[64 * 64];    // cells x k  (8KB)
    __shared__ __align__(16) __half Bs[128 * 64];   // batch x k  (16KB)
    const int tid = threadIdx.x;
    int orig = blockIdx.y * gridDim.x + blockIdx.x;
    int wgid = xcd_swz(orig, 8 * NTC);
    const int b0 = (wgid & 7) * 128;
    const int c0 = (wgid >> 3) * 64;
    const int wid = tid >> 6, lane = tid & 63;
    const int wc = wid >> 2;           // 0..1 -> 32-cell half
    const int wb = wid & 3;            // 0..3 -> 32-batch quarter
    const int g4 = lane >> 4, l16 = lane & 15;

    f32x4 acc[2][2] = {};

    for (int k0 = 0; k0 < D_; k0 += 64) {
        if (k0) __syncthreads();
        {   // A: 64 rows x 8 units = 512 (one shot)
            int row = tid >> 3, u = tid & 7;
            int ug = (u ^ (row & 7)) * 8;
            int cc = c0 + row; if (cc > NC - 1) cc = NC - 1;
            gl_lds16(&wh[(size_t)cc * D_ + k0 + ug], &As[(tid & ~63) * 8]);
        }
        #pragma unroll
        for (int r = 0; r < 2; ++r) {   // B: 128 rows x 8 units = 1024
            int f = tid + r * 512;
            int row = f >> 3, u = f & 7;
            int ug = (u ^ (row & 7)) * 8;
            gl_lds16(&xh[(size_t)(b0 + row) * D_ + k0 + ug], &Bs[(f & ~63) * 8]);
        }
        __syncthreads();
        #pragma unroll
        for (int kh = 0; kh < 2; ++kh) {
            int ubase = kh * 4 + g4;
            f16x8 bfr[2];
            #pragma unroll
            for (int fn = 0; fn < 2; ++fn) {
                int rowb = wb * 32 + fn * 16 + l16;
                bfr[fn] = *reinterpret_cast<const f16x8*>(&Bs[rowb * 64 + ((ubase ^ (rowb & 7)) * 8)]);
            }
            #pragma unroll
            for (int fm = 0; fm < 2; ++fm) {
                int rowa = wc * 32 + fm * 16 + l16;
                f16x8 af = *reinterpret_cast<const f16x8*>(&As[rowa * 64 + ((ubase ^ (rowa & 7)) * 8)]);
                #pragma unroll
                for (int fn = 0; fn < 2; ++fn)
                    acc[fm][fn] = __builtin_amdgcn_mfma_f32_16x16x32_f16(af, bfr[fn], acc[fm][fn], 0, 0, 0);
            }
        }
    }

    // store h (dot, fp16) — k_fix shortlists from it (pad region c>=NC never read)
    #pragma unroll
    for (int fm = 0; fm < 2; ++fm) {
        int cb = c0 + wc * 32 + fm * 16 + g4 * 4;
        #pragma unroll
        for (int fn = 0; fn < 2; ++fn) {
            int b = b0 + wb * 32 + fn * 16 + l16;
            __half hv[4];
            #pragma unroll
            for (int r = 0; r < 4; ++r) hv[r] = __float2half(acc[fm][fn][r]);
            *reinterpret_cast<uint2*>(&h[(size_t)b * LD + cb]) = *reinterpret_cast<uint2*>(hv);
        }
    }

    // fused min1: per-lane reduce over fm,r; shfl across g4; one atomic per column
    // (wnorm[cb>=NC] = +inf pad -> phantom cells never win; pad covers 10048)
    ull best[2] = {~0ull, ~0ull};
    #pragma unroll
    for (int fm = 0; fm < 2; ++fm) {
        int cb = c0 + wc * 32 + fm * 16 + g4 * 4;
        float4 wn4 = *reinterpret_cast<const float4*>(&wnorm[cb]);
        float wna[4] = {wn4.x, wn4.y, wn4.z, wn4.w};
        #pragma unroll
        for (int fn = 0; fn < 2; ++fn)
            #pragma unroll
            for (int r = 0; r < 4; ++r) {
                float s = wna[r] - 2.0f * acc[fm][fn][r];
                ull p = ((ull)fkey(s) << 32) | (unsigned)(cb + r);
                if (p < best[fn]) best[fn] = p;
            }
    }
    #pragma unroll
    for (int fn = 0; fn < 2; ++fn) {
        ull o = __shfl_xor(best[fn], 16); best[fn] = o < best[fn] ? o : best[fn];
        o = __shfl_xor(best[fn], 32);     best[fn] = o < best[fn] ? o : best[fn];
    }
    if (g4 == 0) {
        atomicMin(&pk1[b0 + wb * 32 + l16], best[0]);
        atomicMin(&pk1[b0 + wb * 32 + 16 + l16], best[1]);
    }
}

// always-on fix (R5/R13-proven): shortlist cells within FIXMARGIN of approx min,
// exact fp32 dots, block-local reduce, write bxy directly
__global__ __launch_bounds__(256) void k_fix(const __half* __restrict__ h, const float* __restrict__ wnorm,
                                             const float* __restrict__ x, const float* __restrict__ w,
                                             const ull* __restrict__ pk1, int2* __restrict__ bxy) {
    __shared__ int cnt;
    __shared__ int cand[SHORTCAP];
    __shared__ ull sbest[4];
    int b = blockIdx.x, tid = threadIdx.x;
    if (tid == 0) cnt = 0;
    __syncthreads();
    float thr = unfkey((unsigned)(pk1[b] >> 32)) + FIXMARGIN;
    for (int ch = 0; ch < 10; ++ch) {
        int c = ch * 1024 + tid * 4;
        if (c < NC) {
            __half hv[4];
            *reinterpret_cast<uint2*>(hv) = *reinterpret_cast<const uint2*>(&h[(size_t)b * LD + c]);
            float4 wn = *reinterpret_cast<const float4*>(&wnorm[c]);
            float we[4] = {wn.x, wn.y, wn.z, wn.w};
            #pragma unroll
            for (int e = 0; e < 4; ++e) {
                float s = we[e] - 2.0f * (float)hv[e];
                if (s <= thr) {
                    int p = atomicAdd(&cnt, 1);
                    if (p < SHORTCAP) cand[p] = c + e;
                }
            }
        }
    }
    __syncthreads();
    int n = cnt;
    int wid = tid >> 6, lane = tid & 63;
    float4 xv = *reinterpret_cast<const float4*>(&x[(size_t)b * D_ + lane * 4]);
    ull best = ~0ull;
    if (n <= SHORTCAP) {
        for (int i = wid; i < n; i += 4) {
            int c = cand[i];
            float4 wv = *reinterpret_cast<const float4*>(&w[(size_t)c * D_ + lane * 4]);
            float p = wv.x * (wv.x - 2.0f * xv.x) + wv.y * (wv.y - 2.0f * xv.y)
                    + wv.z * (wv.z - 2.0f * xv.z) + wv.w * (wv.w - 2.0f * xv.w);
            #pragma unroll
            for (int off = 32; off; off >>= 1) p += __shfl_xor(p, off);
            if (lane == 0) {
                ull pk = ((ull)fkey(p) << 32) | (unsigned)c;
                best = pk < best ? pk : best;
            }
        }
    } else {  // pathological overflow: full exact scan (deterministic, ~never taken)
        for (int c = wid; c < NC; c += 4) {
            float4 wv = *reinterpret_cast<const float4*>(&w[(size_t)c * D_ + lane * 4]);
            float p = wv.x * (wv.x - 2.0f * xv.x) + wv.y * (wv.y - 2.0f * xv.y)
                    + wv.z * (wv.z - 2.0f * xv.z) + wv.w * (wv.w - 2.0f * xv.w);
            #pragma unroll
            for (int off = 32; off; off >>= 1) p += __shfl_xor(p, off);
            if (lane == 0) {
                ull pk = ((ull)fkey(p) << 32) | (unsigned)c;
                best = pk < best ? pk : best;
            }
        }
    }
    if (lane == 0) sbest[wid] = best;
    __syncthreads();
    if (tid == 0) {
        ull bb = sbest[0];
        #pragma unroll
        for (int k = 1; k < 4; ++k) bb = sbest[k] < bb ? sbest[k] : bb;
        int c = (int)(unsigned)(bb & 0xffffffffull);
        bxy[b] = make_int2(c / W_, c % W_);
    }
}

// chunked 2-pass suffix scan with separable-Gaussian LDS table
__global__ __launch_bounds__(256) void k_scan(const int2* __restrict__ bxy, const int* __restrict__ ep,
                                              const int* __restrict__ tp, ushort_t* __restrict__ coefT,
                                              float* __restrict__ T) {
    __shared__ float E[W_];
    float lr, inv2r2;
    decay_params(ep, tp, lr, inv2r2);
    if (threadIdx.x < W_) {
        float d = (float)threadIdx.x;
        E[threadIdx.x] = __expf(-d * d * inv2r2);
    }
    __syncthreads();

    int g = blockIdx.x * 256 + threadIdx.x;
    int c = g >> 3, t = g & 7;
    if (c >= NC) return;
    int cy = c / W_, cx = c % W_;
    int base = t * 128;

    float P = 1.0f;
    for (int i = base; i < base + 128; ++i) {
        int2 p = bxy[i];
        int dy = abs(p.x - cy), dx = abs(p.y - cx);
        float a = lr * E[dy] * E[dx];
        P *= (1.0f - a);
    }
    int gbase = (threadIdx.x & 63) & ~7;
    float M = 1.0f;
    #pragma unroll
    for (int k = 1; k < 8; ++k) {
        float pk = __shfl(P, gbase + k, 64);
        if (k > t) M *= pk;
    }
    if (t == 0) T[c] = M * P;

    float s = M;
    for (int seg = 15; seg >= 0; --seg) {
        ushort_t buf[8];
        #pragma unroll
        for (int e = 7; e >= 0; --e) {
            int i = base + seg * 8 + e;
            int2 p = bxy[i];
            int dy = abs(p.x - cy), dx = abs(p.y - cx);
            float a = lr * E[dy] * E[dx];
            buf[e] = f2bf(a * s);
            s *= (1.0f - a);
        }
        *reinterpret_cast<uint4*>(&coefT[(size_t)c * B_ + base + seg * 8]) =
            *reinterpret_cast<uint4*>(buf);
    }
}

// update GEMM via bf16 MFMA: tile 32 cells x 64 d, BK=64, 4 waves (16c x 32d each),
// single-buffer gl_lds staging — grid 1252 blocks (~4.9/CU) for latency hiding
__global__ __launch_bounds__(256) void k_update(const ushort_t* __restrict__ coefT, const ushort_t* __restrict__ xhT,
                                                const float* __restrict__ T, const float* __restrict__ w0,
                                                float* __restrict__ out) {
    __shared__ __align__(16) ushort_t As[32 * 64];   // 4KB
    __shared__ __align__(16) ushort_t Bs[64 * 64];   // 8KB
    const int tid = threadIdx.x;
    int orig = blockIdx.y * gridDim.x + blockIdx.x;
    int wgid = xcd_swz(orig, 4 * 313);
    const int d0 = (wgid & 3) * 64;
    const int c0 = (wgid >> 2) * 32;
    const int wid = tid >> 6, lane = tid & 63;
    const int wc = wid >> 1, wd = wid & 1;   // wc: 16-cell half, wd: 32-d half
    const int g4 = lane >> 4, l16 = lane & 15;

    f32x4 acc[2] = {};

    for (int k0 = 0; k0 < B_; k0 += 64) {
        if (k0) __syncthreads();
        {   // A: 32 rows x 8 units = 256 (one shot)
            int row = tid >> 3, u = tid & 7;
            int ug = (u ^ (row & 7)) * 8;
            int cc = c0 + row; if (cc > NC - 1) cc = NC - 1;
            gl_lds16(&coefT[(size_t)cc * B_ + k0 + ug], &As[(tid & ~63) * 8]);
        }
        #pragma unroll
        for (int r = 0; r < 2; ++r) {   // B: 64 rows x 8 units = 512
            int f = tid + r * 256;
            int row = f >> 3, u = f & 7;
            int ug = (u ^ (row & 7)) * 8;
            gl_lds16(&xhT[(size_t)(d0 + row) * B_ + k0 + ug], &Bs[(f & ~63) * 8]);
        }
        __syncthreads();
        #pragma unroll
        for (int kh = 0; kh < 2; ++kh) {
            int ubase = kh * 4 + g4;
            int rowa = wc * 16 + l16;
            bf16x8 af = *reinterpret_cast<const bf16x8*>(&As[rowa * 64 + ((ubase ^ (rowa & 7)) * 8)]);
            #pragma unroll
            for (int fn = 0; fn < 2; ++fn) {
                int rowb = wd * 32 + fn * 16 + l16;
                bf16x8 bfr = *reinterpret_cast<const bf16x8*>(&Bs[rowb * 64 + ((ubase ^ (rowb & 7)) * 8)]);
                acc[fn] = __builtin_amdgcn_mfma_f32_16x16x32_bf16(af, bfr, acc[fn], 0, 0, 0);
            }
        }
    }

    #pragma unroll
    for (int r = 0; r < 4; ++r) {
        int c = c0 + wc * 16 + g4 * 4 + r;
        if (c < NC) {
            float t = T[c];
            #pragma unroll
            for (int fn = 0; fn < 2; ++fn) {
                int d = d0 + wd * 32 + fn * 16 + l16;
                out[(size_t)c * D_ + d] = fmaf(t, w0[(size_t)c * D_ + d], acc[fn][r]);
            }
        }
    }
}

// ---------- tiny-ws fallback path ----------
__global__ void k_initfix(ull* packed_fix) {
    int i = blockIdx.x * 256 + threadIdx.x;
    if (i < B_) packed_fix[i] = ~0ull;
}
__global__ __launch_bounds__(256) void k_exact_bmu(const float* __restrict__ x, const float* __restrict__ w,
                                                   ull* __restrict__ packed_fix) {
    int b = blockIdx.x;
    int wid = threadIdx.x >> 6, lane = threadIdx.x & 63;
    float4 xv = *reinterpret_cast<const float4*>(&x[(size_t)b * D_ + lane * 4]);
    ull best = ~0ull;
    for (int c = wid; c < NC; c += 4) {
        float4 wv = *reinterpret_cast<const float4*>(&w[(size_t)c * D_ + lane * 4]);
        float p = wv.x * (wv.x - 2.0f * xv.x) + wv.y * (wv.y - 2.0f * xv.y)
                + wv.z * (wv.z - 2.0f * xv.z) + wv.w * (wv.w - 2.0f * xv.w);
        #pragma unroll
        for (int off = 32; off; off >>= 1) p += __shfl_xor(p, off);
        if (lane == 0) {
            ull pk = ((ull)fkey(p) << 32) | (unsigned)c;
            best = pk < best ? pk : best;
        }
    }
    if (lane == 0) atomicMin(&packed_fix[b], best);
}
__global__ void k_decode_force(const ull* __restrict__ packed_fix, float2* __restrict__ xy) {
    int i = blockIdx.x * 256 + threadIdx.x;
    if (i < B_) {
        int c = (int)(unsigned)(packed_fix[i] & 0xffffffffull);
        xy[i] = make_float2((float)(c / W_), (float)(c % W_));
    }
}
__global__ __launch_bounds__(256) void k_update_fallback(const float* __restrict__ x, const float* __restrict__ w0,
                                                         const float2* __restrict__ xy, const int* ep, const int* tp,
                                                         float* __restrict__ out) {
    int c = blockIdx.x;
    int d = threadIdx.x;
    float cyf = (float)(c / W_), cxf = (float)(c % W_);
    float lr, inv2r2;
    decay_params(ep, tp, lr, inv2r2);
    float acc = w0[(size_t)c * D_ + d];
    for (int i = 0; i < B_; ++i) {
        float2 p = xy[i];
        float dy = p.x - cyf, dx = p.y - cxf;
        float a = lr * __expf(-(dy * dy + dx * dx) * inv2r2);
        acc = fmaf(a, x[(size_t)i * D_ + d] - acc, acc);
    }
    out[(size_t)c * D_ + d] = acc;
}

extern "C" void kernel_launch(void* const* d_in, const int* in_sizes, int n_in,
                              void* d_out, int out_size, void* d_ws, size_t ws_size,
                              hipStream_t stream) {
    const float* x = (const float*)d_in[0];
    const float* w = (const float*)d_in[1];
    const int* ep = (const int*)d_in[2];
    const int* tp = (const int*)d_in[3];
    float* out = (float*)d_out;

    char* ws = (char*)d_ws;
    ull* pk1        = (ull*)ws;                      // 8KB    @ 0
    int2* bxy       = (int2*)(ws + 16384);           // 8KB    @ 16K
    float2* xyf     = (float2*)(ws + 16384);         // (fallback alias)
    float* T        = (float*)(ws + 24576);          // 40KB   @ 24K
    float* wnorm    = (float*)(ws + 65536);          // 40.5KB @ 64K (incl +128 pad)
    ushort_t* xhT   = (ushort_t*)(ws + 131072);      // 512KB  @ 128K
    __half* xh      = (__half*)(ws + 655360);        // 512KB
    __half* wh      = (__half*)(ws + 1179648);       // 5.12MB
    ushort_t* coefT = (ushort_t*)(ws + 6553600);     // 20.48MB
    __half* h       = (__half*)(ws + 27262976);      // 20.97MB
    size_t required = 27262976 + (size_t)B_ * LD * 2;  // ~48.2MB

    if (ws_size >= required) {
        k_prep<<<NC / 4 + 64 + 1, 256, 0, stream>>>(w, x, wh, wnorm, xh, xhT, pk1);
        k_scores_mfma<<<dim3(8, NTC), 512, 0, stream>>>(wh, xh, wnorm, h, pk1);
        k_fix<<<B_, 256, 0, stream>>>(h, wnorm, x, w, pk1, bxy);
        k_scan<<<(NC * 8 + 255) / 256, 256, 0, stream>>>(bxy, ep, tp, coefT, T);
        k_update<<<dim3(4, 313), 256, 0, stream>>>(coefT, xhT, T, w, out);
    } else {
        k_initfix<<<4, 256, 0, stream>>>(pk1);
        k_exact_bmu<<<B_, 256, 0, stream>>>(x, w, pk1);
        k_decode_force<<<4, 256, 0, stream>>>(pk1, xyf);
        k_update_fallback<<<NC, 256, 0, stream>>>(x, w, xyf, ep, tp, out);
    }
}